// Round 2
// baseline (199.670 us; speedup 1.0000x reference)
//
#include <hip/hip_runtime.h>
#include <stdint.h>

// ---- types ----
typedef short s16x8 __attribute__((ext_vector_type(8)));
typedef float f32x4 __attribute__((ext_vector_type(4)));
typedef unsigned int u32x4 __attribute__((ext_vector_type(4)));

// log2(e) / sqrt(128): fold softmax scale + exp2 conversion into Q projection
#define QSCALE 0.12751743f

__device__ __forceinline__ unsigned short f2bf(float f) {
  unsigned int u = __builtin_bit_cast(unsigned int, f);
  u += 0x7fffu + ((u >> 16) & 1u);   // RNE
  return (unsigned short)(u >> 16);
}

__device__ __forceinline__ f32x4 mfma16(s16x8 a, s16x8 b, f32x4 c) {
  return __builtin_amdgcn_mfma_f32_16x16x32_bf16(a, b, c, 0, 0, 0);
}

// async global->LDS DMA, 16B/lane, dest = wave-uniform base + lane*16
#define GLD(GP, LP)                                                            \
  __builtin_amdgcn_global_load_lds(                                            \
      (const __attribute__((address_space(1))) unsigned int*)(GP),             \
      (__attribute__((address_space(3))) unsigned int*)(LP), 16, 0, 0)

// ============ kernel 1: weights fp32 -> bf16, K-chunk-tiled (identity) ======
// Wt layout: [kc(32k)][n(384)][4 granules, granule gk = k-local/8][8 elems]
// No swizzle: proj_k now reads fragments straight from global (no LDS), so
// bank-conflict swizzling is unnecessary and identity granules make each
// per-wave fragment read a fully coalesced contiguous 1KB.
__global__ __launch_bounds__(256) void wconv_k(const float* __restrict__ Wq,
                                               const float* __restrict__ Wk,
                                               const float* __restrict__ Wv,
                                               unsigned short* __restrict__ Wt) {
  int idx = (blockIdx.x * 256 + threadIdx.x) * 4;   // 393216 elems
  int tensor = idx >> 17;
  int r = idx & 131071;
  const float* src = tensor == 0 ? Wq : (tensor == 1 ? Wk : Wv);
  float4 f = *(const float4*)(src + r);
  float sc = (tensor == 0) ? QSCALE : 1.0f;
  ushort4 o;
  o.x = f2bf(f.x * sc); o.y = f2bf(f.y * sc);
  o.z = f2bf(f.z * sc); o.w = f2bf(f.w * sc);
  int nl = r >> 10, k = r & 1023;
  int n = tensor * 128 + nl;
  int kc = k >> 5, kl = k & 31, gk = kl >> 3, j = kl & 7;  // j in {0,4}
  *(ushort4*)(Wt + kc * 12288 + (n * 4 + gk) * 8 + j) = o;
}

// ============ kernel 2: QKV projection GEMM (M=16384, N=384, K=1024) ========
// Register-streaming, LDS-free, BARRIER-free. Old version was latency-bound:
// __syncthreads forces s_waitcnt vmcnt(0) before s_barrier every BK=32 chunk,
// so each of 32 chunks paid full L2/L3 load latency against only ~150cy of
// work (MfmaUtil 8%, 72% idle). Now each wave loads its private W slab
// (6 x 16B/lane, contiguous 1KB/instr) and its x fragments (16 rows x 64B
// windows, L1-amortized across the 4 waves) straight to VGPRs with a manual
// depth-2 register pipeline: loads for kc+2/kc+3 stay in flight under the
// MFMAs of kc/kc+1, no drain points anywhere.
__global__ __launch_bounds__(256, 2) void proj_k(const float* __restrict__ x,
    const float* __restrict__ bq, const float* __restrict__ bk,
    const float* __restrict__ bv, const unsigned short* __restrict__ Wt,
    unsigned short* __restrict__ Qg, unsigned short* __restrict__ KVg) {
  const int tid = threadIdx.x;
  const int wv = tid >> 6, ln = tid & 15, quad = (tid >> 4) & 3;
  const int mt = blockIdx.x;

  float bias[6];
  int tensor_[6], hcol_[6];
#pragma unroll
  for (int nt = 0; nt < 6; nt++) {
    int g_nt = wv * 6 + nt;
    int tensor = g_nt >> 3;
    int hcol = ((g_nt & 7) << 4) + ln;
    tensor_[nt] = tensor; hcol_[nt] = hcol;
    bias[nt] = (tensor == 0) ? bq[hcol] * QSCALE : (tensor == 1 ? bk[hcol] : bv[hcol]);
  }

  f32x4 acc[2][6];
  f32x4 zero = {0.f, 0.f, 0.f, 0.f};
#pragma unroll
  for (int m = 0; m < 2; m++)
#pragma unroll
    for (int nt = 0; nt < 6; nt++) acc[m][nt] = zero;

  // A-frag: lane(ln,quad) owns row m*16+ln, k = kc*32 + quad*8 .. +7 (fp32).
  // B-frag: lane(ln,quad) owns col (wv*6+nt)*16+ln, granule quad (8 bf16).
  const float* xp0 = x + (size_t)(mt * 32 + ln) * 1024 + quad * 8;
  const float* xp1 = xp0 + 16 * 1024;
  const unsigned short* wp = Wt + ((size_t)(wv * 96 + ln) * 4 + quad) * 8;

  float4 xA[2][2], xB[2][2];
  u32x4 wA[6], wB[6];

#define PJ_LOAD(XR, WR, KC)                                                    \
  {                                                                            \
    XR[0][0] = *(const float4*)(xp0 + (KC) * 32);                              \
    XR[0][1] = *(const float4*)(xp0 + (KC) * 32 + 4);                          \
    XR[1][0] = *(const float4*)(xp1 + (KC) * 32);                              \
    XR[1][1] = *(const float4*)(xp1 + (KC) * 32 + 4);                          \
    _Pragma("unroll") for (int nt_ = 0; nt_ < 6; nt_++)                        \
      WR[nt_] = *(const u32x4*)(wp + (size_t)(KC) * 12288 + nt_ * 512);        \
  }

#define PJ_COMP(XR, WR)                                                        \
  {                                                                            \
    s16x8 a_[2];                                                               \
    _Pragma("unroll") for (int m_ = 0; m_ < 2; m_++) {                         \
      u32x4 af;                                                                \
      af.x = f2bf(XR[m_][0].x) | ((unsigned)f2bf(XR[m_][0].y) << 16);          \
      af.y = f2bf(XR[m_][0].z) | ((unsigned)f2bf(XR[m_][0].w) << 16);          \
      af.z = f2bf(XR[m_][1].x) | ((unsigned)f2bf(XR[m_][1].y) << 16);          \
      af.w = f2bf(XR[m_][1].z) | ((unsigned)f2bf(XR[m_][1].w) << 16);          \
      a_[m_] = __builtin_bit_cast(s16x8, af);                                  \
    }                                                                          \
    _Pragma("unroll") for (int nt_ = 0; nt_ < 6; nt_++) {                      \
      s16x8 b_ = __builtin_bit_cast(s16x8, WR[nt_]);                           \
      _Pragma("unroll") for (int m_ = 0; m_ < 2; m_++)                         \
        acc[m_][nt_] = mfma16(a_[m_], b_, acc[m_][nt_]);                       \
    }                                                                          \
  }

  PJ_LOAD(xA, wA, 0);
  PJ_LOAD(xB, wB, 1);
  for (int kc = 0; kc < 28; kc += 2) {   // guard-free body: loads hoistable
    PJ_COMP(xA, wA);
    PJ_LOAD(xA, wA, kc + 2);
    PJ_COMP(xB, wB);
    PJ_LOAD(xB, wB, kc + 3);
  }
  PJ_COMP(xA, wA);   // kc=28
  PJ_LOAD(xA, wA, 30);
  PJ_COMP(xB, wB);   // kc=29
  PJ_LOAD(xB, wB, 31);
  PJ_COMP(xA, wA);   // kc=30
  PJ_COMP(xB, wB);   // kc=31

  // epilogue: C-layout row = quad*4+reg, col = ln (m89-verified).
  // K tile elem (tr,h): (tr*16 + ghs)*8 + (h&7), ghs = (gh&8)|((gh&7)^(tr&7))
  // V tile elem (tr,h): 4096 + (h*4 + gts)*8 + (tr&7), gts = (tr>>3)^((h>>1)&3)
  const int r0 = mt * 32;
#pragma unroll
  for (int nt = 0; nt < 6; nt++) {
    int hcol = hcol_[nt];
#pragma unroll
    for (int m = 0; m < 2; m++) {
#pragma unroll
      for (int reg = 0; reg < 4; reg++) {
        float val = acc[m][nt][reg] + bias[nt];
        unsigned short h = f2bf(val);
        int rl = m * 16 + quad * 4 + reg;       // 0..31 == tr (32-row tiles)
        int t_abs = r0 + rl;
        size_t chbase = (size_t)((t_abs >> 12) * 128 + ((t_abs & 4095) >> 5)) * 8192;
        if (tensor_[nt] == 0) {
          Qg[(size_t)t_abs * 128 + hcol] = h;
        } else if (tensor_[nt] == 1) {
          int gh = hcol >> 3;
          int ghs = (gh & 8) | ((gh & 7) ^ (rl & 7));
          KVg[chbase + (rl * 16 + ghs) * 8 + (hcol & 7)] = h;
        } else {
          int gts = (rl >> 3) ^ ((hcol >> 1) & 3);
          KVg[chbase + 4096 + (hcol * 4 + gts) * 8 + (rl & 7)] = h;
        }
      }
    }
  }
}

// ============ kernel 3: causal attention, DMA-pipelined, no-max softmax =====
// BM=128 (4 waves x 32 rows), BN=32, seg=16 chunks, dense 576-block grid.
// Per chunk: one 16KB combined K/V tile DMA'd linearly (4 x 1KB per wave) into
// dbuf LDS; swizzled layouts give conflict-free b128 fragment reads. One
// barrier per chunk. p = exp2(s); l via ones-B MFMA; bf16 partials.
__global__ __launch_bounds__(256, 3) void attn_k(const unsigned short* __restrict__ Qg,
    const unsigned short* __restrict__ KVg,
    unsigned short* __restrict__ Po, float* __restrict__ Plr) {
  __shared__ unsigned short kvb[2][8192];  // 2 x 16KB (K tile 8KB | V tile 8KB)
  __shared__ unsigned short Pl[128 * 40];  // 10KB, wave-private rows
  const int tid = threadIdx.x;
  const int wv = tid >> 6, ln = tid & 15, quad = (tid >> 4) & 3;
  const int lane = tid & 63;
  const int id = blockIdx.x;               // dense slot, 0..575
  const int b = id / 144;
  int rem = id - b * 144;
  int a_ = 0;
  while (2 * (a_ + 1) * (a_ + 2) <= rem) a_++;       // <=7 scalar iters
  const int off = rem - 2 * a_ * (a_ + 1);
  const int qt = 4 * a_ + off / (a_ + 1);
  const int seg = off - (off / (a_ + 1)) * (a_ + 1);
  const int qbase = qt * 128;
  const int totch = 4 * qt + 4;
  const int nch = min(16, totch - seg * 16);

  const unsigned short* KVb = KVg + (size_t)b * 1048576;  // 128 chunks x 8192 elems

  // Q fragments: 2 m-tiles, A-layout (m=ln, k=quad*8+j + 32*ks)
  u32x4 qf[2][4];
#pragma unroll
  for (int m = 0; m < 2; m++) {
    const int qrow = b * 4096 + qbase + wv * 32 + m * 16 + ln;
#pragma unroll
    for (int ks = 0; ks < 4; ks++)
      qf[m][ks] = *(const u32x4*)((const char*)Qg + (size_t)qrow * 256 + ks * 64 + quad * 16);
  }

  f32x4 o[2][8];
  f32x4 lacc[2];
  f32x4 zero = {0.f, 0.f, 0.f, 0.f};
#pragma unroll
  for (int m = 0; m < 2; m++) {
    lacc[m] = zero;
#pragma unroll
    for (int i = 0; i < 8; i++) o[m][i] = zero;
  }
  const s16x8 onesb = {0x3F80, 0x3F80, 0x3F80, 0x3F80, 0x3F80, 0x3F80, 0x3F80, 0x3F80};

#define ATTN_DMA(BUF, CH)                                                      \
  _Pragma("unroll") for (int i = 0; i < 4; i++) {                              \
    GLD(KVb + (size_t)(CH) * 8192 + (wv * 4 + i) * 512 + lane * 8,             \
        &kvb[BUF][(wv * 4 + i) * 512]);                                        \
  }

  ATTN_DMA(0, seg * 16);
  for (int ci = 0; ci < nch; ci++) {
    const int cur = ci & 1;
    const int ch = seg * 16 + ci;
    const int t0 = ch * 32;
    __syncthreads();                 // DMA(cur) visible; prior reads of cur done
    if (ci + 1 < nch) { ATTN_DMA(cur ^ 1, ch + 1); }

    // S = Q K^T; K frag (t = nt*16+ln, granule gh = ks*4+quad, swizzled)
    f32x4 s[2][2];
#pragma unroll
    for (int m = 0; m < 2; m++)
#pragma unroll
      for (int nt = 0; nt < 2; nt++) s[m][nt] = zero;
#pragma unroll
    for (int ks = 0; ks < 4; ks++)
#pragma unroll
      for (int nt = 0; nt < 2; nt++) {
        int t = nt * 16 + ln;
        int gh = ks * 4 + quad;
        int ghs = (gh & 8) | ((gh & 7) ^ (t & 7));
        s16x8 kf = __builtin_bit_cast(s16x8, *(const u32x4*)&kvb[cur][(t * 16 + ghs) * 8]);
#pragma unroll
        for (int m = 0; m < 2; m++)
          s[m][nt] = mfma16(__builtin_bit_cast(s16x8, qf[m][ks]), kf, s[m][nt]);
      }

    // causal mask (diagonal-touching chunks; fully-masked chunks -> p=0)
    if (t0 + 31 > qbase + wv * 32) {
#pragma unroll
      for (int m = 0; m < 2; m++)
#pragma unroll
        for (int nt = 0; nt < 2; nt++)
#pragma unroll
          for (int reg = 0; reg < 4; reg++) {
            int kidx = t0 + nt * 16 + ln;
            int qidx = qbase + wv * 32 + m * 16 + quad * 4 + reg;
            if (kidx > qidx) s[m][nt][reg] = -1e30f;
          }
    }

    // p = exp2(s) -> bf16 -> wave-private LDS (C->A layout round-trip)
#pragma unroll
    for (int m = 0; m < 2; m++)
#pragma unroll
      for (int nt = 0; nt < 2; nt++)
#pragma unroll
        for (int reg = 0; reg < 4; reg++) {
          float pv = __builtin_amdgcn_exp2f(s[m][nt][reg]);
          Pl[(wv * 32 + m * 16 + quad * 4 + reg) * 40 + nt * 16 + ln] = f2bf(pv);
        }

    // PV + l accumulation; V frag (h = nh*16+ln, granule gt = quad, swizzled)
    s16x8 pa[2];
#pragma unroll
    for (int m = 0; m < 2; m++)
      pa[m] = __builtin_bit_cast(s16x8,
          *(const u32x4*)&Pl[(wv * 32 + m * 16 + ln) * 40 + quad * 8]);
#pragma unroll
    for (int nh = 0; nh < 8; nh++) {
      int h = nh * 16 + ln;
      int gts = quad ^ ((h >> 1) & 3);
      s16x8 vf = __builtin_bit_cast(s16x8,
          *(const u32x4*)&kvb[cur][4096 + (h * 4 + gts) * 8]);
#pragma unroll
      for (int m = 0; m < 2; m++)
        o[m][nh] = mfma16(pa[m], vf, o[m][nh]);
    }
#pragma unroll
    for (int m = 0; m < 2; m++)
      lacc[m] = mfma16(pa[m], onesb, lacc[m]);
  }

  // epilogue: bf16 unnormalized partial + fp32 row sums
  unsigned short* po = Po + (size_t)id * 16384;
#pragma unroll
  for (int m = 0; m < 2; m++) {
#pragma unroll
    for (int reg = 0; reg < 4; reg++) {
      int rowl = wv * 32 + m * 16 + quad * 4 + reg;
#pragma unroll
      for (int nh = 0; nh < 8; nh++)
        po[rowl * 128 + nh * 16 + ln] = f2bf(o[m][nh][reg]);
      if (ln == 0) Plr[id * 128 + rowl] = lacc[m][reg];
    }
  }
}

// ============ kernel 4: combine bf16 partials (pure sums, coalesced) ========
__global__ __launch_bounds__(256) void combine_k(const unsigned short* __restrict__ Po,
    const float* __restrict__ Plr, float* __restrict__ out) {
  const int id = blockIdx.x;
  const int tileid = id >> 2, quarter = id & 3;
  const int qt = tileid & 31;
  const int b = tileid >> 5;
  const int a_ = qt >> 2, r_ = qt & 3;
  const int base = b * 144 + 2 * a_ * (a_ + 1) + r_ * (a_ + 1);
  const int nseg = a_ + 1;
  const int tid = threadIdx.x;
#pragma unroll
  for (int i = 0; i < 2; i++) {
    int g = quarter * 512 + i * 256 + tid;   // granule of 8 elems; 2048/tile
    int row = g >> 4;
    float acc[8] = {0.f, 0.f, 0.f, 0.f, 0.f, 0.f, 0.f, 0.f};
    float L = 0.f;
    for (int s = 0; s < nseg; s++) {
      u32x4 u = *(const u32x4*)(Po + (size_t)(base + s) * 16384 + g * 8);
      L += Plr[(base + s) * 128 + row];
      acc[0] += __builtin_bit_cast(float, u.x << 16);
      acc[1] += __builtin_bit_cast(float, u.x & 0xffff0000u);
      acc[2] += __builtin_bit_cast(float, u.y << 16);
      acc[3] += __builtin_bit_cast(float, u.y & 0xffff0000u);
      acc[4] += __builtin_bit_cast(float, u.z << 16);
      acc[5] += __builtin_bit_cast(float, u.z & 0xffff0000u);
      acc[6] += __builtin_bit_cast(float, u.w << 16);
      acc[7] += __builtin_bit_cast(float, u.w & 0xffff0000u);
    }
    float inv = 1.f / L;
    float* op = out + (size_t)tileid * 16384 + g * 8;
    f32x4 o0 = {acc[0] * inv, acc[1] * inv, acc[2] * inv, acc[3] * inv};
    f32x4 o1 = {acc[4] * inv, acc[5] * inv, acc[6] * inv, acc[7] * inv};
    *(f32x4*)op = o0;
    *(f32x4*)(op + 4) = o1;
  }
}

// ============ launch ============
extern "C" void kernel_launch(void* const* d_in, const int* in_sizes, int n_in,
                              void* d_out, int out_size, void* d_ws, size_t ws_size,
                              hipStream_t stream) {
  const float* x  = (const float*)d_in[0];
  const float* Wq = (const float*)d_in[1];
  const float* bq = (const float*)d_in[2];
  const float* bk = (const float*)d_in[4];
  const float* Wk = (const float*)d_in[3];
  const float* Wv = (const float*)d_in[5];
  const float* bv = (const float*)d_in[6];
  float* out = (float*)d_out;

  char* wsb = (char*)d_ws;
  unsigned short* Wt  = (unsigned short*)wsb;                 // 768 KB (tiled W)
  unsigned short* Qg  = (unsigned short*)(wsb + 786432);      // 4 MB
  unsigned short* KVg = (unsigned short*)(wsb + 4980736);     // 8 MB (512 x 16KB tiles)
  unsigned short* Po  = (unsigned short*)(wsb + 13369344);    // 18.9 MB (576 slots, bf16)
  float* Plr = (float*)(wsb + 32243712);                      // 288 KB

  wconv_k<<<dim3(384), dim3(256), 0, stream>>>(Wq, Wk, Wv, Wt);
  proj_k<<<dim3(512), dim3(256), 0, stream>>>(x, bq, bk, bv, Wt, Qg, KVg);
  attn_k<<<dim3(576), dim3(256), 0, stream>>>(Qg, KVg, Po, Plr);
  combine_k<<<dim3(512), dim3(256), 0, stream>>>(Po, Plr, out);
}

// Round 3
// 189.095 us; speedup vs baseline: 1.0559x; 1.0559x over previous
//
#include <hip/hip_runtime.h>
#include <stdint.h>

// ---- types ----
typedef short s16x8 __attribute__((ext_vector_type(8)));
typedef float f32x4 __attribute__((ext_vector_type(4)));
typedef unsigned int u32x4 __attribute__((ext_vector_type(4)));

// log2(e) / sqrt(128): fold softmax scale + exp2 conversion into Q projection
#define QSCALE 0.12751743f

__device__ __forceinline__ unsigned short f2bf(float f) {
  unsigned int u = __builtin_bit_cast(unsigned int, f);
  u += 0x7fffu + ((u >> 16) & 1u);   // RNE
  return (unsigned short)(u >> 16);
}

__device__ __forceinline__ f32x4 mfma16(s16x8 a, s16x8 b, f32x4 c) {
  return __builtin_amdgcn_mfma_f32_16x16x32_bf16(a, b, c, 0, 0, 0);
}

// async global->LDS DMA, 16B/lane, dest = wave-uniform base + lane*16
#define GLD(GP, LP)                                                            \
  __builtin_amdgcn_global_load_lds(                                            \
      (const __attribute__((address_space(1))) unsigned int*)(GP),             \
      (__attribute__((address_space(3))) unsigned int*)(LP), 16, 0, 0)

// ============ kernel 1: weights fp32 -> bf16, K-chunk-tiled + swizzled ======
// Wt layout: [kc(32k)][n(384)][4 granules, col = gk ^ ((n>>1)&3)][8 elems]
__global__ __launch_bounds__(256) void wconv_k(const float* __restrict__ Wq,
                                               const float* __restrict__ Wk,
                                               const float* __restrict__ Wv,
                                               unsigned short* __restrict__ Wt) {
  int idx = (blockIdx.x * 256 + threadIdx.x) * 4;   // 393216 elems
  int tensor = idx >> 17;
  int r = idx & 131071;
  const float* src = tensor == 0 ? Wq : (tensor == 1 ? Wk : Wv);
  float4 f = *(const float4*)(src + r);
  float sc = (tensor == 0) ? QSCALE : 1.0f;
  ushort4 o;
  o.x = f2bf(f.x * sc); o.y = f2bf(f.y * sc);
  o.z = f2bf(f.z * sc); o.w = f2bf(f.w * sc);
  int nl = r >> 10, k = r & 1023;
  int n = tensor * 128 + nl;
  int kc = k >> 5, kl = k & 31, gk = kl >> 3, j = kl & 7;  // j in {0,4}
  int gks = gk ^ ((n >> 1) & 3);
  *(ushort4*)(Wt + kc * 12288 + (n * 4 + gks) * 8 + j) = o;
}

// ============ kernel 2: QKV projection GEMM (M=16384, N=384, K=1024) ========
// v3: BM=64 rows x N-half=192 cols per block; 512 blocks x 256 threads
// (4 waves, each owning 3 n-tiles). Same proven DMA-dbuf-barrier structure as
// the 55us round-0 kernel (register-streaming variant regressed: compiler
// collapsed the pipeline at 84 VGPR + scattered 4KB-stride x reads).
// Per chunk/CU staged bytes drop 64KB->40KB and total W streaming halves
// (393MB -> 196MB of L2 traffic) while occupancy stays 8 waves/CU.
__global__ __launch_bounds__(256, 2) void proj_k(const float* __restrict__ x,
    const float* __restrict__ bq, const float* __restrict__ bk,
    const float* __restrict__ bv, const unsigned short* __restrict__ Wt,
    unsigned short* __restrict__ Qg, unsigned short* __restrict__ KVg) {
  __shared__ unsigned int xb[2][2048];       // 2 x 8KB: x chunk [64r][8 gx swz] fp32
  __shared__ unsigned short wb[2][6144];     // 2 x 12KB: W half-chunk [192n][4 gk swz]
  const int tid = threadIdx.x;
  const int wv = tid >> 6, ln = tid & 15, quad = (tid >> 4) & 3;
  const int lane = tid & 63;
  const int mt = blockIdx.x >> 1;            // 0..255: rows mt*64..+63
  const int nh = blockIdx.x & 1;             // N half: n-tiles nh*12..+11

  float bias[3];
  int tensor_[3], hcol_[3];
#pragma unroll
  for (int nt = 0; nt < 3; nt++) {
    int g_nt = nh * 12 + wv * 3 + nt;        // global n-tile 0..23
    int tensor = g_nt >> 3;
    int hcol = ((g_nt & 7) << 4) + ln;
    tensor_[nt] = tensor; hcol_[nt] = hcol;
    bias[nt] = (tensor == 0) ? bq[hcol] * QSCALE : (tensor == 1 ? bk[hcol] : bv[hcol]);
  }

  f32x4 acc[4][3];
  f32x4 zero = {0.f, 0.f, 0.f, 0.f};
#pragma unroll
  for (int m = 0; m < 4; m++)
#pragma unroll
    for (int nt = 0; nt < 3; nt++) acc[m][nt] = zero;

  // x DMA: 512 granules (64 rows x 8 slots of 16B); slot s holds global
  // granule gx = s ^ (row&7) (swizzle baked into per-lane global src addr).
  // W DMA: 3 contiguous 1KB instrs/wave from the block's N-half (global
  // already swizzled by wconv_k).
#define PJ_DMA(BUF, KC)                                                        \
  _Pragma("unroll") for (int i = 0; i < 2; i++) {                              \
    int idx = wv * 128 + i * 64 + lane;                                        \
    int r_ = idx >> 3, gx = (idx & 7) ^ (r_ & 7);                              \
    GLD(x + (size_t)(mt * 64 + r_) * 1024 + (KC) * 32 + gx * 4,                \
        &xb[BUF][(wv * 128 + i * 64) * 4]);                                    \
  }                                                                            \
  _Pragma("unroll") for (int i = 0; i < 3; i++) {                              \
    GLD(Wt + (size_t)(KC) * 12288 + ((nh * 12 + wv * 3 + i) * 64 + lane) * 8,  \
        &wb[BUF][(wv * 3 + i) * 512]);                                         \
  }

  PJ_DMA(0, 0);
  for (int kc = 0; kc < 32; kc++) {
    const int cur = kc & 1;
    __syncthreads();                 // DMA(cur) complete; prior reads done
    if (kc + 1 < 32) { PJ_DMA(cur ^ 1, kc + 1); }

    s16x8 a[4];
#pragma unroll
    for (int m = 0; m < 4; m++) {
      int r_ = m * 16 + ln;
      int c0 = (quad * 2) ^ (r_ & 7);
      int c1 = c0 ^ 1;
      f32x4 lo = *(const f32x4*)&xb[cur][(r_ * 8 + c0) * 4];
      f32x4 hi = *(const f32x4*)&xb[cur][(r_ * 8 + c1) * 4];
      u32x4 af;
      af.x = f2bf(lo.x) | ((unsigned)f2bf(lo.y) << 16);
      af.y = f2bf(lo.z) | ((unsigned)f2bf(lo.w) << 16);
      af.z = f2bf(hi.x) | ((unsigned)f2bf(hi.y) << 16);
      af.w = f2bf(hi.z) | ((unsigned)f2bf(hi.w) << 16);
      a[m] = __builtin_bit_cast(s16x8, af);
    }
#pragma unroll
    for (int nt = 0; nt < 3; nt++) {
      int nloc = (wv * 3 + nt) * 16 + ln;          // local col 0..191
      int gks = quad ^ ((ln >> 1) & 3);            // (n>>1)&3 == (ln>>1)&3
      s16x8 b = __builtin_bit_cast(s16x8, *(const u32x4*)&wb[cur][(nloc * 4 + gks) * 8]);
#pragma unroll
      for (int m = 0; m < 4; m++)
        acc[m][nt] = mfma16(a[m], b, acc[m][nt]);
    }
  }

  // epilogue: C-layout row = quad*4+reg (+m*16), col = ln (m89-verified).
  // K tile elem (tr,h): (tr*16 + ghs)*8 + (h&7), ghs = (gh&8)|((gh&7)^(tr&7))
  // V tile elem (tr,h): 4096 + (h*4 + gts)*8 + (tr&7), gts = (tr>>3)^((h>>1)&3)
  const int r0 = mt * 64;
#pragma unroll
  for (int nt = 0; nt < 3; nt++) {
    int hcol = hcol_[nt];
#pragma unroll
    for (int m = 0; m < 4; m++) {
#pragma unroll
      for (int reg = 0; reg < 4; reg++) {
        float val = acc[m][nt][reg] + bias[nt];
        unsigned short h = f2bf(val);
        int rl = m * 16 + quad * 4 + reg;       // 0..63
        int t_abs = r0 + rl;
        int tr = rl & 31;                        // row within 32-key chunk
        size_t chbase = (size_t)((t_abs >> 12) * 128 + ((t_abs & 4095) >> 5)) * 8192;
        if (tensor_[nt] == 0) {
          Qg[(size_t)t_abs * 128 + hcol] = h;
        } else if (tensor_[nt] == 1) {
          int gh = hcol >> 3;
          int ghs = (gh & 8) | ((gh & 7) ^ (tr & 7));
          KVg[chbase + (tr * 16 + ghs) * 8 + (hcol & 7)] = h;
        } else {
          int gts = (tr >> 3) ^ ((hcol >> 1) & 3);
          KVg[chbase + 4096 + (hcol * 4 + gts) * 8 + (tr & 7)] = h;
        }
      }
    }
  }
}

// ============ kernel 3: causal attention, DMA-pipelined, no-max softmax =====
// BM=128 (4 waves x 32 rows), BN=32, seg=16 chunks, dense 576-block grid.
// Per chunk: one 16KB combined K/V tile DMA'd linearly (4 x 1KB per wave) into
// dbuf LDS; swizzled layouts give conflict-free b128 fragment reads. One
// barrier per chunk. p = exp2(s); l via ones-B MFMA; bf16 partials.
__global__ __launch_bounds__(256, 3) void attn_k(const unsigned short* __restrict__ Qg,
    const unsigned short* __restrict__ KVg,
    unsigned short* __restrict__ Po, float* __restrict__ Plr) {
  __shared__ unsigned short kvb[2][8192];  // 2 x 16KB (K tile 8KB | V tile 8KB)
  __shared__ unsigned short Pl[128 * 40];  // 10KB, wave-private rows
  const int tid = threadIdx.x;
  const int wv = tid >> 6, ln = tid & 15, quad = (tid >> 4) & 3;
  const int lane = tid & 63;
  const int id = blockIdx.x;               // dense slot, 0..575
  const int b = id / 144;
  int rem = id - b * 144;
  int a_ = 0;
  while (2 * (a_ + 1) * (a_ + 2) <= rem) a_++;       // <=7 scalar iters
  const int off = rem - 2 * a_ * (a_ + 1);
  const int qt = 4 * a_ + off / (a_ + 1);
  const int seg = off - (off / (a_ + 1)) * (a_ + 1);
  const int qbase = qt * 128;
  const int totch = 4 * qt + 4;
  const int nch = min(16, totch - seg * 16);

  const unsigned short* KVb = KVg + (size_t)b * 1048576;  // 128 chunks x 8192 elems

  // Q fragments: 2 m-tiles, A-layout (m=ln, k=quad*8+j + 32*ks)
  u32x4 qf[2][4];
#pragma unroll
  for (int m = 0; m < 2; m++) {
    const int qrow = b * 4096 + qbase + wv * 32 + m * 16 + ln;
#pragma unroll
    for (int ks = 0; ks < 4; ks++)
      qf[m][ks] = *(const u32x4*)((const char*)Qg + (size_t)qrow * 256 + ks * 64 + quad * 16);
  }

  f32x4 o[2][8];
  f32x4 lacc[2];
  f32x4 zero = {0.f, 0.f, 0.f, 0.f};
#pragma unroll
  for (int m = 0; m < 2; m++) {
    lacc[m] = zero;
#pragma unroll
    for (int i = 0; i < 8; i++) o[m][i] = zero;
  }
  const s16x8 onesb = {0x3F80, 0x3F80, 0x3F80, 0x3F80, 0x3F80, 0x3F80, 0x3F80, 0x3F80};

#define ATTN_DMA(BUF, CH)                                                      \
  _Pragma("unroll") for (int i = 0; i < 4; i++) {                              \
    GLD(KVb + (size_t)(CH) * 8192 + (wv * 4 + i) * 512 + lane * 8,             \
        &kvb[BUF][(wv * 4 + i) * 512]);                                        \
  }

  ATTN_DMA(0, seg * 16);
  for (int ci = 0; ci < nch; ci++) {
    const int cur = ci & 1;
    const int ch = seg * 16 + ci;
    const int t0 = ch * 32;
    __syncthreads();                 // DMA(cur) visible; prior reads of cur done
    if (ci + 1 < nch) { ATTN_DMA(cur ^ 1, ch + 1); }

    // S = Q K^T; K frag (t = nt*16+ln, granule gh = ks*4+quad, swizzled)
    f32x4 s[2][2];
#pragma unroll
    for (int m = 0; m < 2; m++)
#pragma unroll
      for (int nt = 0; nt < 2; nt++) s[m][nt] = zero;
#pragma unroll
    for (int ks = 0; ks < 4; ks++)
#pragma unroll
      for (int nt = 0; nt < 2; nt++) {
        int t = nt * 16 + ln;
        int gh = ks * 4 + quad;
        int ghs = (gh & 8) | ((gh & 7) ^ (t & 7));
        s16x8 kf = __builtin_bit_cast(s16x8, *(const u32x4*)&kvb[cur][(t * 16 + ghs) * 8]);
#pragma unroll
        for (int m = 0; m < 2; m++)
          s[m][nt] = mfma16(__builtin_bit_cast(s16x8, qf[m][ks]), kf, s[m][nt]);
      }

    // causal mask (diagonal-touching chunks; fully-masked chunks -> p=0)
    if (t0 + 31 > qbase + wv * 32) {
#pragma unroll
      for (int m = 0; m < 2; m++)
#pragma unroll
        for (int nt = 0; nt < 2; nt++)
#pragma unroll
          for (int reg = 0; reg < 4; reg++) {
            int kidx = t0 + nt * 16 + ln;
            int qidx = qbase + wv * 32 + m * 16 + quad * 4 + reg;
            if (kidx > qidx) s[m][nt][reg] = -1e30f;
          }
    }

    // p = exp2(s) -> bf16 -> wave-private LDS (C->A layout round-trip)
#pragma unroll
    for (int m = 0; m < 2; m++)
#pragma unroll
      for (int nt = 0; nt < 2; nt++)
#pragma unroll
        for (int reg = 0; reg < 4; reg++) {
          float pv = __builtin_amdgcn_exp2f(s[m][nt][reg]);
          Pl[(wv * 32 + m * 16 + quad * 4 + reg) * 40 + nt * 16 + ln] = f2bf(pv);
        }

    // PV + l accumulation; V frag (h = nh*16+ln, granule gt = quad, swizzled)
    s16x8 pa[2];
#pragma unroll
    for (int m = 0; m < 2; m++)
      pa[m] = __builtin_bit_cast(s16x8,
          *(const u32x4*)&Pl[(wv * 32 + m * 16 + ln) * 40 + quad * 8]);
#pragma unroll
    for (int nh = 0; nh < 8; nh++) {
      int h = nh * 16 + ln;
      int gts = quad ^ ((h >> 1) & 3);
      s16x8 vf = __builtin_bit_cast(s16x8,
          *(const u32x4*)&kvb[cur][4096 + (h * 4 + gts) * 8]);
#pragma unroll
      for (int m = 0; m < 2; m++)
        o[m][nh] = mfma16(pa[m], vf, o[m][nh]);
    }
#pragma unroll
    for (int m = 0; m < 2; m++)
      lacc[m] = mfma16(pa[m], onesb, lacc[m]);
  }

  // epilogue: bf16 unnormalized partial + fp32 row sums
  unsigned short* po = Po + (size_t)id * 16384;
#pragma unroll
  for (int m = 0; m < 2; m++) {
#pragma unroll
    for (int reg = 0; reg < 4; reg++) {
      int rowl = wv * 32 + m * 16 + quad * 4 + reg;
#pragma unroll
      for (int nh = 0; nh < 8; nh++)
        po[rowl * 128 + nh * 16 + ln] = f2bf(o[m][nh][reg]);
      if (ln == 0) Plr[id * 128 + rowl] = lacc[m][reg];
    }
  }
}

// ============ kernel 4: combine bf16 partials (pure sums, coalesced) ========
__global__ __launch_bounds__(256) void combine_k(const unsigned short* __restrict__ Po,
    const float* __restrict__ Plr, float* __restrict__ out) {
  const int id = blockIdx.x;
  const int tileid = id >> 2, quarter = id & 3;
  const int qt = tileid & 31;
  const int b = tileid >> 5;
  const int a_ = qt >> 2, r_ = qt & 3;
  const int base = b * 144 + 2 * a_ * (a_ + 1) + r_ * (a_ + 1);
  const int nseg = a_ + 1;
  const int tid = threadIdx.x;
#pragma unroll
  for (int i = 0; i < 2; i++) {
    int g = quarter * 512 + i * 256 + tid;   // granule of 8 elems; 2048/tile
    int row = g >> 4;
    float acc[8] = {0.f, 0.f, 0.f, 0.f, 0.f, 0.f, 0.f, 0.f};
    float L = 0.f;
    for (int s = 0; s < nseg; s++) {
      u32x4 u = *(const u32x4*)(Po + (size_t)(base + s) * 16384 + g * 8);
      L += Plr[(base + s) * 128 + row];
      acc[0] += __builtin_bit_cast(float, u.x << 16);
      acc[1] += __builtin_bit_cast(float, u.x & 0xffff0000u);
      acc[2] += __builtin_bit_cast(float, u.y << 16);
      acc[3] += __builtin_bit_cast(float, u.y & 0xffff0000u);
      acc[4] += __builtin_bit_cast(float, u.z << 16);
      acc[5] += __builtin_bit_cast(float, u.z & 0xffff0000u);
      acc[6] += __builtin_bit_cast(float, u.w << 16);
      acc[7] += __builtin_bit_cast(float, u.w & 0xffff0000u);
    }
    float inv = 1.f / L;
    float* op = out + (size_t)tileid * 16384 + g * 8;
    f32x4 o0 = {acc[0] * inv, acc[1] * inv, acc[2] * inv, acc[3] * inv};
    f32x4 o1 = {acc[4] * inv, acc[5] * inv, acc[6] * inv, acc[7] * inv};
    *(f32x4*)op = o0;
    *(f32x4*)(op + 4) = o1;
  }
}

// ============ launch ============
extern "C" void kernel_launch(void* const* d_in, const int* in_sizes, int n_in,
                              void* d_out, int out_size, void* d_ws, size_t ws_size,
                              hipStream_t stream) {
  const float* x  = (const float*)d_in[0];
  const float* Wq = (const float*)d_in[1];
  const float* bq = (const float*)d_in[2];
  const float* Wk = (const float*)d_in[3];
  const float* bk = (const float*)d_in[4];
  const float* Wv = (const float*)d_in[5];
  const float* bv = (const float*)d_in[6];
  float* out = (float*)d_out;

  char* wsb = (char*)d_ws;
  unsigned short* Wt  = (unsigned short*)wsb;                 // 768 KB (tiled W)
  unsigned short* Qg  = (unsigned short*)(wsb + 786432);      // 4 MB
  unsigned short* KVg = (unsigned short*)(wsb + 4980736);     // 8 MB (512 x 16KB tiles)
  unsigned short* Po  = (unsigned short*)(wsb + 13369344);    // 18.9 MB (576 slots, bf16)
  float* Plr = (float*)(wsb + 32243712);                      // 288 KB

  wconv_k<<<dim3(384), dim3(256), 0, stream>>>(Wq, Wk, Wv, Wt);
  proj_k<<<dim3(512), dim3(256), 0, stream>>>(x, bq, bk, bv, Wt, Qg, KVg);
  attn_k<<<dim3(576), dim3(256), 0, stream>>>(Qg, KVg, Po, Plr);
  combine_k<<<dim3(512), dim3(256), 0, stream>>>(Po, Plr, out);
}

// Round 5
// 182.416 us; speedup vs baseline: 1.0946x; 1.0366x over previous
//
#include <hip/hip_runtime.h>
#include <stdint.h>

// ---- types ----
typedef short s16x8 __attribute__((ext_vector_type(8)));
typedef float f32x4 __attribute__((ext_vector_type(4)));
typedef unsigned int u32x4 __attribute__((ext_vector_type(4)));

// log2(e) / sqrt(128): fold softmax scale + exp2 conversion into Q projection
#define QSCALE 0.12751743f

__device__ __forceinline__ unsigned short f2bf(float f) {
  unsigned int u = __builtin_bit_cast(unsigned int, f);
  u += 0x7fffu + ((u >> 16) & 1u);   // RNE
  return (unsigned short)(u >> 16);
}

__device__ __forceinline__ f32x4 mfma16(s16x8 a, s16x8 b, f32x4 c) {
  return __builtin_amdgcn_mfma_f32_16x16x32_bf16(a, b, c, 0, 0, 0);
}

// async global->LDS DMA, 16B/lane, dest = wave-uniform base + lane*16
#define GLD(GP, LP)                                                            \
  __builtin_amdgcn_global_load_lds(                                            \
      (const __attribute__((address_space(1))) unsigned int*)(GP),             \
      (__attribute__((address_space(3))) unsigned int*)(LP), 16, 0, 0)

// ============ kernel 1: weights fp32 -> bf16, K-chunk-tiled + swizzled ======
// Wt layout: [kc(32k)][n(384)][4 granules, col = gk ^ ((n>>1)&3)][8 elems]
__global__ __launch_bounds__(256) void wconv_k(const float* __restrict__ Wq,
                                               const float* __restrict__ Wk,
                                               const float* __restrict__ Wv,
                                               unsigned short* __restrict__ Wt) {
  int idx = (blockIdx.x * 256 + threadIdx.x) * 4;   // 393216 elems
  int tensor = idx >> 17;
  int r = idx & 131071;
  const float* src = tensor == 0 ? Wq : (tensor == 1 ? Wk : Wv);
  float4 f = *(const float4*)(src + r);
  float sc = (tensor == 0) ? QSCALE : 1.0f;
  ushort4 o;
  o.x = f2bf(f.x * sc); o.y = f2bf(f.y * sc);
  o.z = f2bf(f.z * sc); o.w = f2bf(f.w * sc);
  int nl = r >> 10, k = r & 1023;
  int n = tensor * 128 + nl;
  int kc = k >> 5, kl = k & 31, gk = kl >> 3, j = kl & 7;  // j in {0,4}
  int gks = gk ^ ((n >> 1) & 3);
  *(ushort4*)(Wt + kc * 12288 + (n * 4 + gks) * 8 + j) = o;
}

// ============ kernel 2: QKV projection GEMM (M=16384, N=384, K=1024) ========
// v4: same BM=64 x N-half=192 geometry as v3 (verified correct), but the sync
// structure is replaced by a 4-deep counted-vmcnt pipeline (T3+T4 / m201
// pattern). v3's counters (MfmaUtil 8%, HBM 17%, conflicts ~0) showed the
// bottleneck is the per-chunk vmcnt(0) drain implied by __syncthreads: every
// chunk paid full HBM latency. Now each wave waits vmcnt(10) -- only for the
// chunk staged 3 iterations earlier -- then raw s_barrier; chunks kc+1/kc+2
// stay in flight across barriers. No vmcnt(0) in the main loop.
__global__ __launch_bounds__(256, 2) void proj_k(const float* __restrict__ x,
    const float* __restrict__ bq, const float* __restrict__ bk,
    const float* __restrict__ bv, const unsigned short* __restrict__ Wt,
    unsigned short* __restrict__ Qg, unsigned short* __restrict__ KVg) {
  __shared__ unsigned int xb[4][2048];       // 4 x 8KB: x chunk [64r][8 gx swz] fp32
  __shared__ unsigned short wb[4][6144];     // 4 x 12KB: W half-chunk [192n][4 gk swz]
  const int tid = threadIdx.x;
  const int wv = tid >> 6, ln = tid & 15, quad = (tid >> 4) & 3;
  const int lane = tid & 63;
  const int mt = blockIdx.x >> 1;            // 0..255: rows mt*64..+63
  const int nh = blockIdx.x & 1;             // N half: n-tiles nh*12..+11

  float bias[3];
  int tensor_[3], hcol_[3];
#pragma unroll
  for (int nt = 0; nt < 3; nt++) {
    int g_nt = nh * 12 + wv * 3 + nt;        // global n-tile 0..23
    int tensor = g_nt >> 3;
    int hcol = ((g_nt & 7) << 4) + ln;
    tensor_[nt] = tensor; hcol_[nt] = hcol;
    bias[nt] = (tensor == 0) ? bq[hcol] * QSCALE : (tensor == 1 ? bk[hcol] : bv[hcol]);
  }

  f32x4 acc[4][3];
  f32x4 zero = {0.f, 0.f, 0.f, 0.f};
#pragma unroll
  for (int m = 0; m < 4; m++)
#pragma unroll
    for (int nt = 0; nt < 3; nt++) acc[m][nt] = zero;

  // x DMA: 512 granules (64 rows x 8 slots of 16B); slot s holds global
  // granule gx = s ^ (row&7) (swizzle baked into per-lane global src addr).
  // W DMA: 3 contiguous 1KB instrs/wave from the block's N-half.
  // 5 GLD per wave per chunk.
#define PJ_DMA(BUF, KC)                                                        \
  _Pragma("unroll") for (int i = 0; i < 2; i++) {                              \
    int idx = wv * 128 + i * 64 + lane;                                        \
    int r_ = idx >> 3, gx = (idx & 7) ^ (r_ & 7);                              \
    GLD(x + (size_t)(mt * 64 + r_) * 1024 + (KC) * 32 + gx * 4,                \
        &xb[BUF][(wv * 128 + i * 64) * 4]);                                    \
  }                                                                            \
  _Pragma("unroll") for (int i = 0; i < 3; i++) {                              \
    GLD(Wt + (size_t)(KC) * 12288 + ((nh * 12 + wv * 3 + i) * 64 + lane) * 8,  \
        &wb[BUF][(wv * 3 + i) * 512]);                                         \
  }

  PJ_DMA(0, 0);
  PJ_DMA(1, 1);
  PJ_DMA(2, 2);
  for (int kc = 0; kc < 32; kc++) {
    const int cur = kc & 3;
    // Wait for own chunk-kc loads only (10 newer loads may stay in flight),
    // then barrier => all waves' chunk-kc slices are resident in LDS.
    if (kc < 30) {
      asm volatile("s_waitcnt vmcnt(10)" ::: "memory");
    } else if (kc == 30) {
      asm volatile("s_waitcnt vmcnt(5)" ::: "memory");
    } else {
      asm volatile("s_waitcnt vmcnt(0)" ::: "memory");
    }
    __builtin_amdgcn_s_barrier();
    __builtin_amdgcn_sched_barrier(0);

    s16x8 a[4];
#pragma unroll
    for (int m = 0; m < 4; m++) {
      int r_ = m * 16 + ln;
      int c0 = (quad * 2) ^ (r_ & 7);
      int c1 = c0 ^ 1;
      f32x4 lo = *(const f32x4*)&xb[cur][(r_ * 8 + c0) * 4];
      f32x4 hi = *(const f32x4*)&xb[cur][(r_ * 8 + c1) * 4];
      u32x4 af;
      af.x = f2bf(lo.x) | ((unsigned)f2bf(lo.y) << 16);
      af.y = f2bf(lo.z) | ((unsigned)f2bf(lo.w) << 16);
      af.z = f2bf(hi.x) | ((unsigned)f2bf(hi.y) << 16);
      af.w = f2bf(hi.z) | ((unsigned)f2bf(hi.w) << 16);
      a[m] = __builtin_bit_cast(s16x8, af);
    }
#pragma unroll
    for (int nt = 0; nt < 3; nt++) {
      int nloc = (wv * 3 + nt) * 16 + ln;          // local col 0..191
      int gks = quad ^ ((ln >> 1) & 3);            // (n>>1)&3 == (ln>>1)&3
      s16x8 b = __builtin_bit_cast(s16x8, *(const u32x4*)&wb[cur][(nloc * 4 + gks) * 8]);
#pragma unroll
      for (int m = 0; m < 4; m++)
        acc[m][nt] = mfma16(a[m], b, acc[m][nt]);
    }

    // Stage chunk kc+3 into buf[(kc-1)&3]; safe: barrier(kc) guaranteed every
    // wave finished compute(kc-1) (reads of that buffer) before this issues.
    if (kc <= 28) { PJ_DMA((kc + 3) & 3, kc + 3); }
  }

  // epilogue: C-layout row = quad*4+reg (+m*16), col = ln (m89-verified).
  // K tile elem (tr,h): (tr*16 + ghs)*8 + (h&7), ghs = (gh&8)|((gh&7)^(tr&7))
  // V tile elem (tr,h): 4096 + (h*4 + gts)*8 + (tr&7), gts = (tr>>3)^((h>>1)&3)
  const int r0 = mt * 64;
#pragma unroll
  for (int nt = 0; nt < 3; nt++) {
    int hcol = hcol_[nt];
#pragma unroll
    for (int m = 0; m < 4; m++) {
#pragma unroll
      for (int reg = 0; reg < 4; reg++) {
        float val = acc[m][nt][reg] + bias[nt];
        unsigned short h = f2bf(val);
        int rl = m * 16 + quad * 4 + reg;       // 0..63
        int t_abs = r0 + rl;
        int tr = rl & 31;                        // row within 32-key chunk
        size_t chbase = (size_t)((t_abs >> 12) * 128 + ((t_abs & 4095) >> 5)) * 8192;
        if (tensor_[nt] == 0) {
          Qg[(size_t)t_abs * 128 + hcol] = h;
        } else if (tensor_[nt] == 1) {
          int gh = hcol >> 3;
          int ghs = (gh & 8) | ((gh & 7) ^ (tr & 7));
          KVg[chbase + (tr * 16 + ghs) * 8 + (hcol & 7)] = h;
        } else {
          int gts = (tr >> 3) ^ ((hcol >> 1) & 3);
          KVg[chbase + 4096 + (hcol * 4 + gts) * 8 + (tr & 7)] = h;
        }
      }
    }
  }
}

// ============ kernel 3: causal attention, DMA-pipelined, no-max softmax =====
// BM=128 (4 waves x 32 rows), BN=32, seg=16 chunks, dense 576-block grid.
// Per chunk: one 16KB combined K/V tile DMA'd linearly (4 x 1KB per wave) into
// dbuf LDS; swizzled layouts give conflict-free b128 fragment reads. One
// barrier per chunk. p = exp2(s); l via ones-B MFMA; bf16 partials.
__global__ __launch_bounds__(256, 3) void attn_k(const unsigned short* __restrict__ Qg,
    const unsigned short* __restrict__ KVg,
    unsigned short* __restrict__ Po, float* __restrict__ Plr) {
  __shared__ unsigned short kvb[2][8192];  // 2 x 16KB (K tile 8KB | V tile 8KB)
  __shared__ unsigned short Pl[128 * 40];  // 10KB, wave-private rows
  const int tid = threadIdx.x;
  const int wv = tid >> 6, ln = tid & 15, quad = (tid >> 4) & 3;
  const int lane = tid & 63;
  const int id = blockIdx.x;               // dense slot, 0..575
  const int b = id / 144;
  int rem = id - b * 144;
  int a_ = 0;
  while (2 * (a_ + 1) * (a_ + 2) <= rem) a_++;       // <=7 scalar iters
  const int off = rem - 2 * a_ * (a_ + 1);
  const int qt = 4 * a_ + off / (a_ + 1);
  const int seg = off - (off / (a_ + 1)) * (a_ + 1);
  const int qbase = qt * 128;
  const int totch = 4 * qt + 4;
  const int nch = min(16, totch - seg * 16);

  const unsigned short* KVb = KVg + (size_t)b * 1048576;  // 128 chunks x 8192 elems

  // Q fragments: 2 m-tiles, A-layout (m=ln, k=quad*8+j + 32*ks)
  u32x4 qf[2][4];
#pragma unroll
  for (int m = 0; m < 2; m++) {
    const int qrow = b * 4096 + qbase + wv * 32 + m * 16 + ln;
#pragma unroll
    for (int ks = 0; ks < 4; ks++)
      qf[m][ks] = *(const u32x4*)((const char*)Qg + (size_t)qrow * 256 + ks * 64 + quad * 16);
  }

  f32x4 o[2][8];
  f32x4 lacc[2];
  f32x4 zero = {0.f, 0.f, 0.f, 0.f};
#pragma unroll
  for (int m = 0; m < 2; m++) {
    lacc[m] = zero;
#pragma unroll
    for (int i = 0; i < 8; i++) o[m][i] = zero;
  }
  const s16x8 onesb = {0x3F80, 0x3F80, 0x3F80, 0x3F80, 0x3F80, 0x3F80, 0x3F80, 0x3F80};

#define ATTN_DMA(BUF, CH)                                                      \
  _Pragma("unroll") for (int i = 0; i < 4; i++) {                              \
    GLD(KVb + (size_t)(CH) * 8192 + (wv * 4 + i) * 512 + lane * 8,             \
        &kvb[BUF][(wv * 4 + i) * 512]);                                        \
  }

  ATTN_DMA(0, seg * 16);
  for (int ci = 0; ci < nch; ci++) {
    const int cur = ci & 1;
    const int ch = seg * 16 + ci;
    const int t0 = ch * 32;
    __syncthreads();                 // DMA(cur) visible; prior reads of cur done
    if (ci + 1 < nch) { ATTN_DMA(cur ^ 1, ch + 1); }

    // S = Q K^T; K frag (t = nt*16+ln, granule gh = ks*4+quad, swizzled)
    f32x4 s[2][2];
#pragma unroll
    for (int m = 0; m < 2; m++)
#pragma unroll
      for (int nt = 0; nt < 2; nt++) s[m][nt] = zero;
#pragma unroll
    for (int ks = 0; ks < 4; ks++)
#pragma unroll
      for (int nt = 0; nt < 2; nt++) {
        int t = nt * 16 + ln;
        int gh = ks * 4 + quad;
        int ghs = (gh & 8) | ((gh & 7) ^ (t & 7));
        s16x8 kf = __builtin_bit_cast(s16x8, *(const u32x4*)&kvb[cur][(t * 16 + ghs) * 8]);
#pragma unroll
        for (int m = 0; m < 2; m++)
          s[m][nt] = mfma16(__builtin_bit_cast(s16x8, qf[m][ks]), kf, s[m][nt]);
      }

    // causal mask (diagonal-touching chunks; fully-masked chunks -> p=0)
    if (t0 + 31 > qbase + wv * 32) {
#pragma unroll
      for (int m = 0; m < 2; m++)
#pragma unroll
        for (int nt = 0; nt < 2; nt++)
#pragma unroll
          for (int reg = 0; reg < 4; reg++) {
            int kidx = t0 + nt * 16 + ln;
            int qidx = qbase + wv * 32 + m * 16 + quad * 4 + reg;
            if (kidx > qidx) s[m][nt][reg] = -1e30f;
          }
    }

    // p = exp2(s) -> bf16 -> wave-private LDS (C->A layout round-trip)
#pragma unroll
    for (int m = 0; m < 2; m++)
#pragma unroll
      for (int nt = 0; nt < 2; nt++)
#pragma unroll
        for (int reg = 0; reg < 4; reg++) {
          float pv = __builtin_amdgcn_exp2f(s[m][nt][reg]);
          Pl[(wv * 32 + m * 16 + quad * 4 + reg) * 40 + nt * 16 + ln] = f2bf(pv);
        }

    // PV + l accumulation; V frag (h = nh*16+ln, granule gt = quad, swizzled)
    s16x8 pa[2];
#pragma unroll
    for (int m = 0; m < 2; m++)
      pa[m] = __builtin_bit_cast(s16x8,
          *(const u32x4*)&Pl[(wv * 32 + m * 16 + ln) * 40 + quad * 8]);
#pragma unroll
    for (int nh = 0; nh < 8; nh++) {
      int h = nh * 16 + ln;
      int gts = quad ^ ((h >> 1) & 3);
      s16x8 vf = __builtin_bit_cast(s16x8,
          *(const u32x4*)&kvb[cur][4096 + (h * 4 + gts) * 8]);
#pragma unroll
      for (int m = 0; m < 2; m++)
        o[m][nh] = mfma16(pa[m], vf, o[m][nh]);
    }
#pragma unroll
    for (int m = 0; m < 2; m++)
      lacc[m] = mfma16(pa[m], onesb, lacc[m]);
  }

  // epilogue: bf16 unnormalized partial + fp32 row sums
  unsigned short* po = Po + (size_t)id * 16384;
#pragma unroll
  for (int m = 0; m < 2; m++) {
#pragma unroll
    for (int reg = 0; reg < 4; reg++) {
      int rowl = wv * 32 + m * 16 + quad * 4 + reg;
#pragma unroll
      for (int nh = 0; nh < 8; nh++)
        po[rowl * 128 + nh * 16 + ln] = f2bf(o[m][nh][reg]);
      if (ln == 0) Plr[id * 128 + rowl] = lacc[m][reg];
    }
  }
}

// ============ kernel 4: combine bf16 partials (pure sums, coalesced) ========
__global__ __launch_bounds__(256) void combine_k(const unsigned short* __restrict__ Po,
    const float* __restrict__ Plr, float* __restrict__ out) {
  const int id = blockIdx.x;
  const int tileid = id >> 2, quarter = id & 3;
  const int qt = tileid & 31;
  const int b = tileid >> 5;
  const int a_ = qt >> 2, r_ = qt & 3;
  const int base = b * 144 + 2 * a_ * (a_ + 1) + r_ * (a_ + 1);
  const int nseg = a_ + 1;
  const int tid = threadIdx.x;
#pragma unroll
  for (int i = 0; i < 2; i++) {
    int g = quarter * 512 + i * 256 + tid;   // granule of 8 elems; 2048/tile
    int row = g >> 4;
    float acc[8] = {0.f, 0.f, 0.f, 0.f, 0.f, 0.f, 0.f, 0.f};
    float L = 0.f;
    for (int s = 0; s < nseg; s++) {
      u32x4 u = *(const u32x4*)(Po + (size_t)(base + s) * 16384 + g * 8);
      L += Plr[(base + s) * 128 + row];
      acc[0] += __builtin_bit_cast(float, u.x << 16);
      acc[1] += __builtin_bit_cast(float, u.x & 0xffff0000u);
      acc[2] += __builtin_bit_cast(float, u.y << 16);
      acc[3] += __builtin_bit_cast(float, u.y & 0xffff0000u);
      acc[4] += __builtin_bit_cast(float, u.z << 16);
      acc[5] += __builtin_bit_cast(float, u.z & 0xffff0000u);
      acc[6] += __builtin_bit_cast(float, u.w << 16);
      acc[7] += __builtin_bit_cast(float, u.w & 0xffff0000u);
    }
    float inv = 1.f / L;
    float* op = out + (size_t)tileid * 16384 + g * 8;
    f32x4 o0 = {acc[0] * inv, acc[1] * inv, acc[2] * inv, acc[3] * inv};
    f32x4 o1 = {acc[4] * inv, acc[5] * inv, acc[6] * inv, acc[7] * inv};
    *(f32x4*)op = o0;
    *(f32x4*)(op + 4) = o1;
  }
}

// ============ launch ============
extern "C" void kernel_launch(void* const* d_in, const int* in_sizes, int n_in,
                              void* d_out, int out_size, void* d_ws, size_t ws_size,
                              hipStream_t stream) {
  const float* x  = (const float*)d_in[0];
  const float* Wq = (const float*)d_in[1];
  const float* bq = (const float*)d_in[2];
  const float* Wk = (const float*)d_in[3];
  const float* bk = (const float*)d_in[4];
  const float* Wv = (const float*)d_in[5];
  const float* bv = (const float*)d_in[6];
  float* out = (float*)d_out;

  char* wsb = (char*)d_ws;
  unsigned short* Wt  = (unsigned short*)wsb;                 // 768 KB (tiled W)
  unsigned short* Qg  = (unsigned short*)(wsb + 786432);      // 4 MB
  unsigned short* KVg = (unsigned short*)(wsb + 4980736);     // 8 MB (512 x 16KB tiles)
  unsigned short* Po  = (unsigned short*)(wsb + 13369344);    // 18.9 MB (576 slots, bf16)
  float* Plr = (float*)(wsb + 32243712);                      // 288 KB

  wconv_k<<<dim3(384), dim3(256), 0, stream>>>(Wq, Wk, Wv, Wt);
  proj_k<<<dim3(512), dim3(256), 0, stream>>>(x, bq, bk, bv, Wt, Qg, KVg);
  attn_k<<<dim3(576), dim3(256), 0, stream>>>(Qg, KVg, Po, Plr);
  combine_k<<<dim3(512), dim3(256), 0, stream>>>(Po, Plr, out);
}

// Round 6
// 178.256 us; speedup vs baseline: 1.1201x; 1.0233x over previous
//
#include <hip/hip_runtime.h>
#include <stdint.h>

// ---- types ----
typedef short s16x8 __attribute__((ext_vector_type(8)));
typedef float f32x4 __attribute__((ext_vector_type(4)));
typedef unsigned int u32x4 __attribute__((ext_vector_type(4)));

// log2(e) / sqrt(128): fold softmax scale + exp2 conversion into Q projection
#define QSCALE 0.12751743f

__device__ __forceinline__ unsigned short f2bf(float f) {
  unsigned int u = __builtin_bit_cast(unsigned int, f);
  u += 0x7fffu + ((u >> 16) & 1u);   // RNE
  return (unsigned short)(u >> 16);
}

__device__ __forceinline__ f32x4 mfma16(s16x8 a, s16x8 b, f32x4 c) {
  return __builtin_amdgcn_mfma_f32_16x16x32_bf16(a, b, c, 0, 0, 0);
}

// async global->LDS DMA, 16B/lane, dest = wave-uniform base + lane*16
#define GLD(GP, LP)                                                            \
  __builtin_amdgcn_global_load_lds(                                            \
      (const __attribute__((address_space(1))) unsigned int*)(GP),             \
      (__attribute__((address_space(3))) unsigned int*)(LP), 16, 0, 0)

// ============ kernel 1: weights fp32 -> bf16, lane-major granule tiles ======
// Wt layout: [kc(32k)][ntile(24)][lane(64)][8 bf16], lane = gk*16 + (n&15).
// A wave's plain coalesced dwordx4 load (addr = base + lane*16) then delivers
// lane (quad,ln) exactly granule (col=ln, k-granule=quad) -- the B-fragment
// layout MFMA wants. No LDS round-trip for W at all.
__global__ __launch_bounds__(256) void wconv_k(const float* __restrict__ Wq,
                                               const float* __restrict__ Wk,
                                               const float* __restrict__ Wv,
                                               unsigned short* __restrict__ Wt) {
  int idx = (blockIdx.x * 256 + threadIdx.x) * 4;   // 393216 elems
  int tensor = idx >> 17;
  int r = idx & 131071;
  const float* src = tensor == 0 ? Wq : (tensor == 1 ? Wk : Wv);
  float4 f = *(const float4*)(src + r);
  float sc = (tensor == 0) ? QSCALE : 1.0f;
  ushort4 o;
  o.x = f2bf(f.x * sc); o.y = f2bf(f.y * sc);
  o.z = f2bf(f.z * sc); o.w = f2bf(f.w * sc);
  int nl = r >> 10, k = r & 1023;
  int n = tensor * 128 + nl;
  int kc = k >> 5, kl = k & 31, gk = kl >> 3, j = kl & 7;  // j in {0,4}
  int ntile = n >> 4;
  int lane_slot = gk * 16 + (n & 15);
  *(ushort4*)(Wt + kc * 12288 + ntile * 512 + lane_slot * 8 + j) = o;
}

// ============ kernel 2: QKV projection GEMM (M=16384, N=384, K=1024) ========
// v5: BM=64 x N-half=192, 512 blocks x 4 waves. W goes global->VGPR directly
// (wave-private slabs, lane-major Wt layout; 4 statically-rotated reg buffers
// via x4-unrolled loop). x stays on the proven GLD->LDS swizzled path, 4 bufs
// x 8KB = 32KB LDS only -> 3 blocks/CU (vs 2): an extra independent barrier
// group per CU to cover each other's waits. Depth-3 counted vmcnt (chunk kc
// waits only for its own 5 ops; kc+1/kc+2 stay in flight). XCD-chunked
// swizzle so mt-pair blocks share x rows in one XCD's L2.
__global__ __launch_bounds__(256, 3) void proj_k(const float* __restrict__ x,
    const float* __restrict__ bq, const float* __restrict__ bk,
    const float* __restrict__ bv, const unsigned short* __restrict__ Wt,
    unsigned short* __restrict__ Qg, unsigned short* __restrict__ KVg) {
  __shared__ unsigned int xb[4][2048];       // 4 x 8KB: x chunk [64r][8 gx swz] fp32
  const int tid = threadIdx.x;
  const int wv = tid >> 6, ln = tid & 15, quad = (tid >> 4) & 3;
  const int lane = tid & 63;
  // bijective XCD-chunked swizzle (512 % 8 == 0): XCD gets 64 consecutive
  // slots = 32 consecutive mt, both nh halves -> x rows shared in-XCD L2.
  const int sw = (blockIdx.x & 7) * 64 + (blockIdx.x >> 3);
  const int mt = sw >> 1;                    // 0..255: rows mt*64..+63
  const int nh = sw & 1;                     // N half: n-tiles nh*12..+11

  float bias[3];
  int tensor_[3], hcol_[3];
#pragma unroll
  for (int nt = 0; nt < 3; nt++) {
    int g_nt = nh * 12 + wv * 3 + nt;        // global n-tile 0..23
    int tensor = g_nt >> 3;
    int hcol = ((g_nt & 7) << 4) + ln;
    tensor_[nt] = tensor; hcol_[nt] = hcol;
    bias[nt] = (tensor == 0) ? bq[hcol] * QSCALE : (tensor == 1 ? bk[hcol] : bv[hcol]);
  }

  f32x4 acc[4][3];
  f32x4 zero = {0.f, 0.f, 0.f, 0.f};
#pragma unroll
  for (int m = 0; m < 4; m++)
#pragma unroll
    for (int nt = 0; nt < 3; nt++) acc[m][nt] = zero;

  // W register buffers: chunk kc lives in Wb[kc&3][*]; all indices static
  // (loop unrolled x4), so these stay in VGPRs (48 total).
  u32x4 Wb[4][3];
  const unsigned short* wpb = Wt + (nh * 12 + wv * 3) * 512 + lane * 8;

  // x DMA: 512 granules (64 rows x 8 slots of 16B); slot s holds global
  // granule gx = s ^ (row&7) (swizzle baked into per-lane global src addr).
  // W: 3 plain coalesced dwordx4 per wave per chunk, straight to VGPRs.
  // 5 vmem ops per wave per chunk total.
#define PJ_STAGE(BUF, KC)                                                      \
  _Pragma("unroll") for (int i = 0; i < 2; i++) {                              \
    int idx = wv * 128 + i * 64 + lane;                                        \
    int r_ = idx >> 3, gx = (idx & 7) ^ (r_ & 7);                              \
    GLD(x + (size_t)(mt * 64 + r_) * 1024 + (KC) * 32 + gx * 4,                \
        &xb[BUF][(wv * 128 + i * 64) * 4]);                                    \
  }                                                                            \
  _Pragma("unroll") for (int i = 0; i < 3; i++) {                              \
    Wb[BUF][i] = *(const u32x4*)(wpb + (size_t)(KC) * 12288 + i * 512);        \
  }

  PJ_STAGE(0, 0);
  PJ_STAGE(1, 1);
  PJ_STAGE(2, 2);
  for (int kcb = 0; kcb < 32; kcb += 4) {
#pragma unroll
    for (int u = 0; u < 4; u++) {
      const int kc = kcb + u;                // kc & 3 == u (kcb % 4 == 0)
      // Wait for chunk kc's own 5 ops only; 10 newer stay in flight.
      if (kc < 30) {
        asm volatile("s_waitcnt vmcnt(10)" ::: "memory");
      } else if (kc == 30) {
        asm volatile("s_waitcnt vmcnt(5)" ::: "memory");
      } else {
        asm volatile("s_waitcnt vmcnt(0)" ::: "memory");
      }
      __builtin_amdgcn_s_barrier();
      __builtin_amdgcn_sched_barrier(0);

      s16x8 a[4];
#pragma unroll
      for (int m = 0; m < 4; m++) {
        int r_ = m * 16 + ln;
        int c0 = (quad * 2) ^ (r_ & 7);
        int c1 = c0 ^ 1;
        f32x4 lo = *(const f32x4*)&xb[u][(r_ * 8 + c0) * 4];
        f32x4 hi = *(const f32x4*)&xb[u][(r_ * 8 + c1) * 4];
        u32x4 af;
        af.x = f2bf(lo.x) | ((unsigned)f2bf(lo.y) << 16);
        af.y = f2bf(lo.z) | ((unsigned)f2bf(lo.w) << 16);
        af.z = f2bf(hi.x) | ((unsigned)f2bf(hi.y) << 16);
        af.w = f2bf(hi.z) | ((unsigned)f2bf(hi.w) << 16);
        a[m] = __builtin_bit_cast(s16x8, af);
      }
#pragma unroll
      for (int nt = 0; nt < 3; nt++) {
        s16x8 b = __builtin_bit_cast(s16x8, Wb[u][nt]);
#pragma unroll
        for (int m = 0; m < 4; m++)
          acc[m][nt] = mfma16(a[m], b, acc[m][nt]);
      }

      // Stage chunk kc+3 into slot (u+3)&3 (chunk kc-1's slot; every wave
      // passed barrier(kc), so all reads of that slot are done). Reg buffer
      // WAR is safe: MFMAs reading Wb[(u+3)&3] issued before these loads.
      if (kc <= 28) { PJ_STAGE((u + 3) & 3, kc + 3); }
    }
  }

  // epilogue: C-layout row = quad*4+reg (+m*16), col = ln (m89-verified).
  // K tile elem (tr,h): (tr*16 + ghs)*8 + (h&7), ghs = (gh&8)|((gh&7)^(tr&7))
  // V tile elem (tr,h): 4096 + (h*4 + gts)*8 + (tr&7), gts = (tr>>3)^((h>>1)&3)
  const int r0 = mt * 64;
#pragma unroll
  for (int nt = 0; nt < 3; nt++) {
    int hcol = hcol_[nt];
#pragma unroll
    for (int m = 0; m < 4; m++) {
#pragma unroll
      for (int reg = 0; reg < 4; reg++) {
        float val = acc[m][nt][reg] + bias[nt];
        unsigned short h = f2bf(val);
        int rl = m * 16 + quad * 4 + reg;       // 0..63
        int t_abs = r0 + rl;
        int tr = rl & 31;                        // row within 32-key chunk
        size_t chbase = (size_t)((t_abs >> 12) * 128 + ((t_abs & 4095) >> 5)) * 8192;
        if (tensor_[nt] == 0) {
          Qg[(size_t)t_abs * 128 + hcol] = h;
        } else if (tensor_[nt] == 1) {
          int gh = hcol >> 3;
          int ghs = (gh & 8) | ((gh & 7) ^ (tr & 7));
          KVg[chbase + (tr * 16 + ghs) * 8 + (hcol & 7)] = h;
        } else {
          int gts = (tr >> 3) ^ ((hcol >> 1) & 3);
          KVg[chbase + 4096 + (hcol * 4 + gts) * 8 + (tr & 7)] = h;
        }
      }
    }
  }
}

// ============ kernel 3: causal attention, DMA-pipelined, no-max softmax =====
// BM=128 (4 waves x 32 rows), BN=32, seg=16 chunks, dense 576-block grid.
// Per chunk: one 16KB combined K/V tile DMA'd linearly (4 x 1KB per wave) into
// dbuf LDS; swizzled layouts give conflict-free b128 fragment reads. One
// barrier per chunk. p = exp2(s); l via ones-B MFMA; bf16 partials.
__global__ __launch_bounds__(256, 3) void attn_k(const unsigned short* __restrict__ Qg,
    const unsigned short* __restrict__ KVg,
    unsigned short* __restrict__ Po, float* __restrict__ Plr) {
  __shared__ unsigned short kvb[2][8192];  // 2 x 16KB (K tile 8KB | V tile 8KB)
  __shared__ unsigned short Pl[128 * 40];  // 10KB, wave-private rows
  const int tid = threadIdx.x;
  const int wv = tid >> 6, ln = tid & 15, quad = (tid >> 4) & 3;
  const int lane = tid & 63;
  const int id = blockIdx.x;               // dense slot, 0..575
  const int b = id / 144;
  int rem = id - b * 144;
  int a_ = 0;
  while (2 * (a_ + 1) * (a_ + 2) <= rem) a_++;       // <=7 scalar iters
  const int off = rem - 2 * a_ * (a_ + 1);
  const int qt = 4 * a_ + off / (a_ + 1);
  const int seg = off - (off / (a_ + 1)) * (a_ + 1);
  const int qbase = qt * 128;
  const int totch = 4 * qt + 4;
  const int nch = min(16, totch - seg * 16);

  const unsigned short* KVb = KVg + (size_t)b * 1048576;  // 128 chunks x 8192 elems

  // Q fragments: 2 m-tiles, A-layout (m=ln, k=quad*8+j + 32*ks)
  u32x4 qf[2][4];
#pragma unroll
  for (int m = 0; m < 2; m++) {
    const int qrow = b * 4096 + qbase + wv * 32 + m * 16 + ln;
#pragma unroll
    for (int ks = 0; ks < 4; ks++)
      qf[m][ks] = *(const u32x4*)((const char*)Qg + (size_t)qrow * 256 + ks * 64 + quad * 16);
  }

  f32x4 o[2][8];
  f32x4 lacc[2];
  f32x4 zero = {0.f, 0.f, 0.f, 0.f};
#pragma unroll
  for (int m = 0; m < 2; m++) {
    lacc[m] = zero;
#pragma unroll
    for (int i = 0; i < 8; i++) o[m][i] = zero;
  }
  const s16x8 onesb = {0x3F80, 0x3F80, 0x3F80, 0x3F80, 0x3F80, 0x3F80, 0x3F80, 0x3F80};

#define ATTN_DMA(BUF, CH)                                                      \
  _Pragma("unroll") for (int i = 0; i < 4; i++) {                              \
    GLD(KVb + (size_t)(CH) * 8192 + (wv * 4 + i) * 512 + lane * 8,             \
        &kvb[BUF][(wv * 4 + i) * 512]);                                        \
  }

  ATTN_DMA(0, seg * 16);
  for (int ci = 0; ci < nch; ci++) {
    const int cur = ci & 1;
    const int ch = seg * 16 + ci;
    const int t0 = ch * 32;
    __syncthreads();                 // DMA(cur) visible; prior reads of cur done
    if (ci + 1 < nch) { ATTN_DMA(cur ^ 1, ch + 1); }

    // S = Q K^T; K frag (t = nt*16+ln, granule gh = ks*4+quad, swizzled)
    f32x4 s[2][2];
#pragma unroll
    for (int m = 0; m < 2; m++)
#pragma unroll
      for (int nt = 0; nt < 2; nt++) s[m][nt] = zero;
#pragma unroll
    for (int ks = 0; ks < 4; ks++)
#pragma unroll
      for (int nt = 0; nt < 2; nt++) {
        int t = nt * 16 + ln;
        int gh = ks * 4 + quad;
        int ghs = (gh & 8) | ((gh & 7) ^ (t & 7));
        s16x8 kf = __builtin_bit_cast(s16x8, *(const u32x4*)&kvb[cur][(t * 16 + ghs) * 8]);
#pragma unroll
        for (int m = 0; m < 2; m++)
          s[m][nt] = mfma16(__builtin_bit_cast(s16x8, qf[m][ks]), kf, s[m][nt]);
      }

    // causal mask (diagonal-touching chunks; fully-masked chunks -> p=0)
    if (t0 + 31 > qbase + wv * 32) {
#pragma unroll
      for (int m = 0; m < 2; m++)
#pragma unroll
        for (int nt = 0; nt < 2; nt++)
#pragma unroll
          for (int reg = 0; reg < 4; reg++) {
            int kidx = t0 + nt * 16 + ln;
            int qidx = qbase + wv * 32 + m * 16 + quad * 4 + reg;
            if (kidx > qidx) s[m][nt][reg] = -1e30f;
          }
    }

    // p = exp2(s) -> bf16 -> wave-private LDS (C->A layout round-trip)
#pragma unroll
    for (int m = 0; m < 2; m++)
#pragma unroll
      for (int nt = 0; nt < 2; nt++)
#pragma unroll
        for (int reg = 0; reg < 4; reg++) {
          float pv = __builtin_amdgcn_exp2f(s[m][nt][reg]);
          Pl[(wv * 32 + m * 16 + quad * 4 + reg) * 40 + nt * 16 + ln] = f2bf(pv);
        }

    // PV + l accumulation; V frag (h = nh*16+ln, granule gt = quad, swizzled)
    s16x8 pa[2];
#pragma unroll
    for (int m = 0; m < 2; m++)
      pa[m] = __builtin_bit_cast(s16x8,
          *(const u32x4*)&Pl[(wv * 32 + m * 16 + ln) * 40 + quad * 8]);
#pragma unroll
    for (int nh = 0; nh < 8; nh++) {
      int h = nh * 16 + ln;
      int gts = quad ^ ((h >> 1) & 3);
      s16x8 vf = __builtin_bit_cast(s16x8,
          *(const u32x4*)&kvb[cur][4096 + (h * 4 + gts) * 8]);
#pragma unroll
      for (int m = 0; m < 2; m++)
        o[m][nh] = mfma16(pa[m], vf, o[m][nh]);
    }
#pragma unroll
    for (int m = 0; m < 2; m++)
      lacc[m] = mfma16(pa[m], onesb, lacc[m]);
  }

  // epilogue: bf16 unnormalized partial + fp32 row sums
  unsigned short* po = Po + (size_t)id * 16384;
#pragma unroll
  for (int m = 0; m < 2; m++) {
#pragma unroll
    for (int reg = 0; reg < 4; reg++) {
      int rowl = wv * 32 + m * 16 + quad * 4 + reg;
#pragma unroll
      for (int nh = 0; nh < 8; nh++)
        po[rowl * 128 + nh * 16 + ln] = f2bf(o[m][nh][reg]);
      if (ln == 0) Plr[id * 128 + rowl] = lacc[m][reg];
    }
  }
}

// ============ kernel 4: combine bf16 partials (pure sums, coalesced) ========
__global__ __launch_bounds__(256) void combine_k(const unsigned short* __restrict__ Po,
    const float* __restrict__ Plr, float* __restrict__ out) {
  const int id = blockIdx.x;
  const int tileid = id >> 2, quarter = id & 3;
  const int qt = tileid & 31;
  const int b = tileid >> 5;
  const int a_ = qt >> 2, r_ = qt & 3;
  const int base = b * 144 + 2 * a_ * (a_ + 1) + r_ * (a_ + 1);
  const int nseg = a_ + 1;
  const int tid = threadIdx.x;
#pragma unroll
  for (int i = 0; i < 2; i++) {
    int g = quarter * 512 + i * 256 + tid;   // granule of 8 elems; 2048/tile
    int row = g >> 4;
    float acc[8] = {0.f, 0.f, 0.f, 0.f, 0.f, 0.f, 0.f, 0.f};
    float L = 0.f;
    for (int s = 0; s < nseg; s++) {
      u32x4 u = *(const u32x4*)(Po + (size_t)(base + s) * 16384 + g * 8);
      L += Plr[(base + s) * 128 + row];
      acc[0] += __builtin_bit_cast(float, u.x << 16);
      acc[1] += __builtin_bit_cast(float, u.x & 0xffff0000u);
      acc[2] += __builtin_bit_cast(float, u.y << 16);
      acc[3] += __builtin_bit_cast(float, u.y & 0xffff0000u);
      acc[4] += __builtin_bit_cast(float, u.z << 16);
      acc[5] += __builtin_bit_cast(float, u.z & 0xffff0000u);
      acc[6] += __builtin_bit_cast(float, u.w << 16);
      acc[7] += __builtin_bit_cast(float, u.w & 0xffff0000u);
    }
    float inv = 1.f / L;
    float* op = out + (size_t)tileid * 16384 + g * 8;
    f32x4 o0 = {acc[0] * inv, acc[1] * inv, acc[2] * inv, acc[3] * inv};
    f32x4 o1 = {acc[4] * inv, acc[5] * inv, acc[6] * inv, acc[7] * inv};
    *(f32x4*)op = o0;
    *(f32x4*)(op + 4) = o1;
  }
}

// ============ launch ============
extern "C" void kernel_launch(void* const* d_in, const int* in_sizes, int n_in,
                              void* d_out, int out_size, void* d_ws, size_t ws_size,
                              hipStream_t stream) {
  const float* x  = (const float*)d_in[0];
  const float* Wq = (const float*)d_in[1];
  const float* bq = (const float*)d_in[2];
  const float* Wk = (const float*)d_in[3];
  const float* bk = (const float*)d_in[4];
  const float* Wv = (const float*)d_in[5];
  const float* bv = (const float*)d_in[6];
  float* out = (float*)d_out;

  char* wsb = (char*)d_ws;
  unsigned short* Wt  = (unsigned short*)wsb;                 // 768 KB (tiled W)
  unsigned short* Qg  = (unsigned short*)(wsb + 786432);      // 4 MB
  unsigned short* KVg = (unsigned short*)(wsb + 4980736);     // 8 MB (512 x 16KB tiles)
  unsigned short* Po  = (unsigned short*)(wsb + 13369344);    // 18.9 MB (576 slots, bf16)
  float* Plr = (float*)(wsb + 32243712);                      // 288 KB

  wconv_k<<<dim3(384), dim3(256), 0, stream>>>(Wq, Wk, Wv, Wt);
  proj_k<<<dim3(512), dim3(256), 0, stream>>>(x, bq, bk, bv, Wt, Qg, KVg);
  attn_k<<<dim3(576), dim3(256), 0, stream>>>(Qg, KVg, Po, Plr);
  combine_k<<<dim3(512), dim3(256), 0, stream>>>(Po, Plr, out);
}

// Round 7
// 177.039 us; speedup vs baseline: 1.1278x; 1.0069x over previous
//
#include <hip/hip_runtime.h>
#include <stdint.h>

// ---- types ----
typedef short s16x8 __attribute__((ext_vector_type(8)));
typedef float f32x4 __attribute__((ext_vector_type(4)));
typedef unsigned int u32x4 __attribute__((ext_vector_type(4)));

// log2(e) / sqrt(128): fold softmax scale + exp2 conversion into Q projection
#define QSCALE 0.12751743f

__device__ __forceinline__ unsigned short f2bf(float f) {
  unsigned int u = __builtin_bit_cast(unsigned int, f);
  u += 0x7fffu + ((u >> 16) & 1u);   // RNE
  return (unsigned short)(u >> 16);
}

__device__ __forceinline__ f32x4 mfma16(s16x8 a, s16x8 b, f32x4 c) {
  return __builtin_amdgcn_mfma_f32_16x16x32_bf16(a, b, c, 0, 0, 0);
}

// async global->LDS DMA, 16B/lane, dest = wave-uniform base + lane*16
#define GLD(GP, LP)                                                            \
  __builtin_amdgcn_global_load_lds(                                            \
      (const __attribute__((address_space(1))) unsigned int*)(GP),             \
      (__attribute__((address_space(3))) unsigned int*)(LP), 16, 0, 0)

// ============ kernel 1: weights fp32 -> bf16, lane-major granule tiles ======
// Wt layout: [kc(32k)][ntile(24)][lane(64)][8 bf16], lane = gk*16 + (n&15).
// A wave's plain coalesced dwordx4 load (addr = base + lane*16) then delivers
// lane (quad,ln) exactly granule (col=ln, k-granule=quad) -- the B-fragment
// layout MFMA wants. No LDS round-trip for W at all.
__global__ __launch_bounds__(256) void wconv_k(const float* __restrict__ Wq,
                                               const float* __restrict__ Wk,
                                               const float* __restrict__ Wv,
                                               unsigned short* __restrict__ Wt) {
  int idx = (blockIdx.x * 256 + threadIdx.x) * 4;   // 393216 elems
  int tensor = idx >> 17;
  int r = idx & 131071;
  const float* src = tensor == 0 ? Wq : (tensor == 1 ? Wk : Wv);
  float4 f = *(const float4*)(src + r);
  float sc = (tensor == 0) ? QSCALE : 1.0f;
  ushort4 o;
  o.x = f2bf(f.x * sc); o.y = f2bf(f.y * sc);
  o.z = f2bf(f.z * sc); o.w = f2bf(f.w * sc);
  int nl = r >> 10, k = r & 1023;
  int n = tensor * 128 + nl;
  int kc = k >> 5, kl = k & 31, gk = kl >> 3, j = kl & 7;  // j in {0,4}
  int ntile = n >> 4;
  int lane_slot = gk * 16 + (n & 15);
  *(ushort4*)(Wt + kc * 12288 + ntile * 512 + lane_slot * 8 + j) = o;
}

// ============ kernel 2: QKV projection GEMM (M=16384, N=384, K=1024) ========
// v5 (best: 46.8us): BM=64 x N-half=192, 512 blocks x 4 waves. W global->VGPR
// direct (wave-private slabs, lane-major Wt; 4 statically-rotated reg bufs).
// x on GLD->LDS swizzled path, 4 x 8KB LDS. Depth-3 counted vmcnt. XCD-chunked
// swizzle (FETCH 67->36MB verified). Three sync structures all land ~47-52us
// with every pipe <30% -- further proj work deprioritized (see attn).
__global__ __launch_bounds__(256, 3) void proj_k(const float* __restrict__ x,
    const float* __restrict__ bq, const float* __restrict__ bk,
    const float* __restrict__ bv, const unsigned short* __restrict__ Wt,
    unsigned short* __restrict__ Qg, unsigned short* __restrict__ KVg) {
  __shared__ unsigned int xb[4][2048];       // 4 x 8KB: x chunk [64r][8 gx swz] fp32
  const int tid = threadIdx.x;
  const int wv = tid >> 6, ln = tid & 15, quad = (tid >> 4) & 3;
  const int lane = tid & 63;
  // bijective XCD-chunked swizzle (512 % 8 == 0): XCD gets 64 consecutive
  // slots = 32 consecutive mt, both nh halves -> x rows shared in-XCD L2.
  const int sw = (blockIdx.x & 7) * 64 + (blockIdx.x >> 3);
  const int mt = sw >> 1;                    // 0..255: rows mt*64..+63
  const int nh = sw & 1;                     // N half: n-tiles nh*12..+11

  float bias[3];
  int tensor_[3], hcol_[3];
#pragma unroll
  for (int nt = 0; nt < 3; nt++) {
    int g_nt = nh * 12 + wv * 3 + nt;        // global n-tile 0..23
    int tensor = g_nt >> 3;
    int hcol = ((g_nt & 7) << 4) + ln;
    tensor_[nt] = tensor; hcol_[nt] = hcol;
    bias[nt] = (tensor == 0) ? bq[hcol] * QSCALE : (tensor == 1 ? bk[hcol] : bv[hcol]);
  }

  f32x4 acc[4][3];
  f32x4 zero = {0.f, 0.f, 0.f, 0.f};
#pragma unroll
  for (int m = 0; m < 4; m++)
#pragma unroll
    for (int nt = 0; nt < 3; nt++) acc[m][nt] = zero;

  // W register buffers: chunk kc lives in Wb[kc&3][*]; all indices static
  // (loop unrolled x4), so these stay in VGPRs (48 total).
  u32x4 Wb[4][3];
  const unsigned short* wpb = Wt + (nh * 12 + wv * 3) * 512 + lane * 8;

  // x DMA: 512 granules (64 rows x 8 slots of 16B); slot s holds global
  // granule gx = s ^ (row&7) (swizzle baked into per-lane global src addr).
  // W: 3 plain coalesced dwordx4 per wave per chunk, straight to VGPRs.
  // 5 vmem ops per wave per chunk total.
#define PJ_STAGE(BUF, KC)                                                      \
  _Pragma("unroll") for (int i = 0; i < 2; i++) {                              \
    int idx = wv * 128 + i * 64 + lane;                                        \
    int r_ = idx >> 3, gx = (idx & 7) ^ (r_ & 7);                              \
    GLD(x + (size_t)(mt * 64 + r_) * 1024 + (KC) * 32 + gx * 4,                \
        &xb[BUF][(wv * 128 + i * 64) * 4]);                                    \
  }                                                                            \
  _Pragma("unroll") for (int i = 0; i < 3; i++) {                              \
    Wb[BUF][i] = *(const u32x4*)(wpb + (size_t)(KC) * 12288 + i * 512);        \
  }

  PJ_STAGE(0, 0);
  PJ_STAGE(1, 1);
  PJ_STAGE(2, 2);
  for (int kcb = 0; kcb < 32; kcb += 4) {
#pragma unroll
    for (int u = 0; u < 4; u++) {
      const int kc = kcb + u;                // kc & 3 == u (kcb % 4 == 0)
      // Wait for chunk kc's own 5 ops only; 10 newer stay in flight.
      if (kc < 30) {
        asm volatile("s_waitcnt vmcnt(10)" ::: "memory");
      } else if (kc == 30) {
        asm volatile("s_waitcnt vmcnt(5)" ::: "memory");
      } else {
        asm volatile("s_waitcnt vmcnt(0)" ::: "memory");
      }
      __builtin_amdgcn_s_barrier();
      __builtin_amdgcn_sched_barrier(0);

      s16x8 a[4];
#pragma unroll
      for (int m = 0; m < 4; m++) {
        int r_ = m * 16 + ln;
        int c0 = (quad * 2) ^ (r_ & 7);
        int c1 = c0 ^ 1;
        f32x4 lo = *(const f32x4*)&xb[u][(r_ * 8 + c0) * 4];
        f32x4 hi = *(const f32x4*)&xb[u][(r_ * 8 + c1) * 4];
        u32x4 af;
        af.x = f2bf(lo.x) | ((unsigned)f2bf(lo.y) << 16);
        af.y = f2bf(lo.z) | ((unsigned)f2bf(lo.w) << 16);
        af.z = f2bf(hi.x) | ((unsigned)f2bf(hi.y) << 16);
        af.w = f2bf(hi.z) | ((unsigned)f2bf(hi.w) << 16);
        a[m] = __builtin_bit_cast(s16x8, af);
      }
#pragma unroll
      for (int nt = 0; nt < 3; nt++) {
        s16x8 b = __builtin_bit_cast(s16x8, Wb[u][nt]);
#pragma unroll
        for (int m = 0; m < 4; m++)
          acc[m][nt] = mfma16(a[m], b, acc[m][nt]);
      }

      // Stage chunk kc+3 into slot (u+3)&3 (chunk kc-1's slot; every wave
      // passed barrier(kc), so all reads of that slot are done). Reg buffer
      // WAR is safe: MFMAs reading Wb[(u+3)&3] issued before these loads.
      if (kc <= 28) { PJ_STAGE((u + 3) & 3, kc + 3); }
    }
  }

  // epilogue: C-layout row = quad*4+reg (+m*16), col = ln (m89-verified).
  // K tile elem (tr,h): (tr*16 + ghs)*8 + (h&7), ghs = (gh&8)|((gh&7)^(tr&7))
  // V tile elem (tr,h): 4096 + (h*4 + gts)*8 + (tr&7), gts = (tr>>3)^((h>>1)&3)
  const int r0 = mt * 64;
#pragma unroll
  for (int nt = 0; nt < 3; nt++) {
    int hcol = hcol_[nt];
#pragma unroll
    for (int m = 0; m < 4; m++) {
#pragma unroll
      for (int reg = 0; reg < 4; reg++) {
        float val = acc[m][nt][reg] + bias[nt];
        unsigned short h = f2bf(val);
        int rl = m * 16 + quad * 4 + reg;       // 0..63
        int t_abs = r0 + rl;
        int tr = rl & 31;                        // row within 32-key chunk
        size_t chbase = (size_t)((t_abs >> 12) * 128 + ((t_abs & 4095) >> 5)) * 8192;
        if (tensor_[nt] == 0) {
          Qg[(size_t)t_abs * 128 + hcol] = h;
        } else if (tensor_[nt] == 1) {
          int gh = hcol >> 3;
          int ghs = (gh & 8) | ((gh & 7) ^ (tr & 7));
          KVg[chbase + (tr * 16 + ghs) * 8 + (hcol & 7)] = h;
        } else {
          int gts = (tr >> 3) ^ ((hcol >> 1) & 3);
          KVg[chbase + 4096 + (hcol * 4 + gts) * 8 + (tr & 7)] = h;
        }
      }
    }
  }
}

// ============ kernel 3: causal attention, DMA-pipelined, no-max softmax =====
// BM=128 (4 waves x 32 rows), BN=32, seg=16 chunks, dense 576-block grid.
// v6: XCD-chunked block swizzle. KVg is 8MB (2MB/batch) but a per-XCD L2 is
// only 4MB; default round-robin puts all 4 batches' KV on every XCD ->
// thrash to L3, and each chunk's DMA latency (~500+cy) exceeds the compute
// phase, stalling every __syncthreads. With id = (bid&7)*72 + (bid>>3)
// (bijective, 576 = 8*72) each XCD owns 72 consecutive slots = half of ONE
// batch's KV = 2MB -> L2-resident, DMA ~200cy, covered by compute.
// id is used for BOTH (b,qt,seg) decode and Po/Plr slot index, so combine_k
// is unchanged.
__global__ __launch_bounds__(256, 3) void attn_k(const unsigned short* __restrict__ Qg,
    const unsigned short* __restrict__ KVg,
    unsigned short* __restrict__ Po, float* __restrict__ Plr) {
  __shared__ unsigned short kvb[2][8192];  // 2 x 16KB (K tile 8KB | V tile 8KB)
  __shared__ unsigned short Pl[128 * 40];  // 10KB, wave-private rows
  const int tid = threadIdx.x;
  const int wv = tid >> 6, ln = tid & 15, quad = (tid >> 4) & 3;
  const int lane = tid & 63;
  const int id = (blockIdx.x & 7) * 72 + (blockIdx.x >> 3);  // XCD-chunked slot
  const int b = id / 144;
  int rem = id - b * 144;
  int a_ = 0;
  while (2 * (a_ + 1) * (a_ + 2) <= rem) a_++;       // <=7 scalar iters
  const int off = rem - 2 * a_ * (a_ + 1);
  const int qt = 4 * a_ + off / (a_ + 1);
  const int seg = off - (off / (a_ + 1)) * (a_ + 1);
  const int qbase = qt * 128;
  const int totch = 4 * qt + 4;
  const int nch = min(16, totch - seg * 16);

  const unsigned short* KVb = KVg + (size_t)b * 1048576;  // 128 chunks x 8192 elems

  // Q fragments: 2 m-tiles, A-layout (m=ln, k=quad*8+j + 32*ks)
  u32x4 qf[2][4];
#pragma unroll
  for (int m = 0; m < 2; m++) {
    const int qrow = b * 4096 + qbase + wv * 32 + m * 16 + ln;
#pragma unroll
    for (int ks = 0; ks < 4; ks++)
      qf[m][ks] = *(const u32x4*)((const char*)Qg + (size_t)qrow * 256 + ks * 64 + quad * 16);
  }

  f32x4 o[2][8];
  f32x4 lacc[2];
  f32x4 zero = {0.f, 0.f, 0.f, 0.f};
#pragma unroll
  for (int m = 0; m < 2; m++) {
    lacc[m] = zero;
#pragma unroll
    for (int i = 0; i < 8; i++) o[m][i] = zero;
  }
  const s16x8 onesb = {0x3F80, 0x3F80, 0x3F80, 0x3F80, 0x3F80, 0x3F80, 0x3F80, 0x3F80};

#define ATTN_DMA(BUF, CH)                                                      \
  _Pragma("unroll") for (int i = 0; i < 4; i++) {                              \
    GLD(KVb + (size_t)(CH) * 8192 + (wv * 4 + i) * 512 + lane * 8,             \
        &kvb[BUF][(wv * 4 + i) * 512]);                                        \
  }

  ATTN_DMA(0, seg * 16);
  for (int ci = 0; ci < nch; ci++) {
    const int cur = ci & 1;
    const int ch = seg * 16 + ci;
    const int t0 = ch * 32;
    __syncthreads();                 // DMA(cur) visible; prior reads of cur done
    if (ci + 1 < nch) { ATTN_DMA(cur ^ 1, ch + 1); }

    // S = Q K^T; K frag (t = nt*16+ln, granule gh = ks*4+quad, swizzled)
    f32x4 s[2][2];
#pragma unroll
    for (int m = 0; m < 2; m++)
#pragma unroll
      for (int nt = 0; nt < 2; nt++) s[m][nt] = zero;
#pragma unroll
    for (int ks = 0; ks < 4; ks++)
#pragma unroll
      for (int nt = 0; nt < 2; nt++) {
        int t = nt * 16 + ln;
        int gh = ks * 4 + quad;
        int ghs = (gh & 8) | ((gh & 7) ^ (t & 7));
        s16x8 kf = __builtin_bit_cast(s16x8, *(const u32x4*)&kvb[cur][(t * 16 + ghs) * 8]);
#pragma unroll
        for (int m = 0; m < 2; m++)
          s[m][nt] = mfma16(__builtin_bit_cast(s16x8, qf[m][ks]), kf, s[m][nt]);
      }

    // causal mask (diagonal-touching chunks; fully-masked chunks -> p=0)
    if (t0 + 31 > qbase + wv * 32) {
#pragma unroll
      for (int m = 0; m < 2; m++)
#pragma unroll
        for (int nt = 0; nt < 2; nt++)
#pragma unroll
          for (int reg = 0; reg < 4; reg++) {
            int kidx = t0 + nt * 16 + ln;
            int qidx = qbase + wv * 32 + m * 16 + quad * 4 + reg;
            if (kidx > qidx) s[m][nt][reg] = -1e30f;
          }
    }

    // p = exp2(s) -> bf16 -> wave-private LDS (C->A layout round-trip)
#pragma unroll
    for (int m = 0; m < 2; m++)
#pragma unroll
      for (int nt = 0; nt < 2; nt++)
#pragma unroll
        for (int reg = 0; reg < 4; reg++) {
          float pv = __builtin_amdgcn_exp2f(s[m][nt][reg]);
          Pl[(wv * 32 + m * 16 + quad * 4 + reg) * 40 + nt * 16 + ln] = f2bf(pv);
        }

    // PV + l accumulation; V frag (h = nh*16+ln, granule gt = quad, swizzled)
    s16x8 pa[2];
#pragma unroll
    for (int m = 0; m < 2; m++)
      pa[m] = __builtin_bit_cast(s16x8,
          *(const u32x4*)&Pl[(wv * 32 + m * 16 + ln) * 40 + quad * 8]);
#pragma unroll
    for (int nh = 0; nh < 8; nh++) {
      int h = nh * 16 + ln;
      int gts = quad ^ ((h >> 1) & 3);
      s16x8 vf = __builtin_bit_cast(s16x8,
          *(const u32x4*)&kvb[cur][4096 + (h * 4 + gts) * 8]);
#pragma unroll
      for (int m = 0; m < 2; m++)
        o[m][nh] = mfma16(pa[m], vf, o[m][nh]);
    }
#pragma unroll
    for (int m = 0; m < 2; m++)
      lacc[m] = mfma16(pa[m], onesb, lacc[m]);
  }

  // epilogue: bf16 unnormalized partial + fp32 row sums
  unsigned short* po = Po + (size_t)id * 16384;
#pragma unroll
  for (int m = 0; m < 2; m++) {
#pragma unroll
    for (int reg = 0; reg < 4; reg++) {
      int rowl = wv * 32 + m * 16 + quad * 4 + reg;
#pragma unroll
      for (int nh = 0; nh < 8; nh++)
        po[rowl * 128 + nh * 16 + ln] = f2bf(o[m][nh][reg]);
      if (ln == 0) Plr[id * 128 + rowl] = lacc[m][reg];
    }
  }
}

// ============ kernel 4: combine bf16 partials (pure sums, coalesced) ========
__global__ __launch_bounds__(256) void combine_k(const unsigned short* __restrict__ Po,
    const float* __restrict__ Plr, float* __restrict__ out) {
  const int id = blockIdx.x;
  const int tileid = id >> 2, quarter = id & 3;
  const int qt = tileid & 31;
  const int b = tileid >> 5;
  const int a_ = qt >> 2, r_ = qt & 3;
  const int base = b * 144 + 2 * a_ * (a_ + 1) + r_ * (a_ + 1);
  const int nseg = a_ + 1;
  const int tid = threadIdx.x;
#pragma unroll
  for (int i = 0; i < 2; i++) {
    int g = quarter * 512 + i * 256 + tid;   // granule of 8 elems; 2048/tile
    int row = g >> 4;
    float acc[8] = {0.f, 0.f, 0.f, 0.f, 0.f, 0.f, 0.f, 0.f};
    float L = 0.f;
    for (int s = 0; s < nseg; s++) {
      u32x4 u = *(const u32x4*)(Po + (size_t)(base + s) * 16384 + g * 8);
      L += Plr[(base + s) * 128 + row];
      acc[0] += __builtin_bit_cast(float, u.x << 16);
      acc[1] += __builtin_bit_cast(float, u.x & 0xffff0000u);
      acc[2] += __builtin_bit_cast(float, u.y << 16);
      acc[3] += __builtin_bit_cast(float, u.y & 0xffff0000u);
      acc[4] += __builtin_bit_cast(float, u.z << 16);
      acc[5] += __builtin_bit_cast(float, u.z & 0xffff0000u);
      acc[6] += __builtin_bit_cast(float, u.w << 16);
      acc[7] += __builtin_bit_cast(float, u.w & 0xffff0000u);
    }
    float inv = 1.f / L;
    float* op = out + (size_t)tileid * 16384 + g * 8;
    f32x4 o0 = {acc[0] * inv, acc[1] * inv, acc[2] * inv, acc[3] * inv};
    f32x4 o1 = {acc[4] * inv, acc[5] * inv, acc[6] * inv, acc[7] * inv};
    *(f32x4*)op = o0;
    *(f32x4*)(op + 4) = o1;
  }
}

// ============ launch ============
extern "C" void kernel_launch(void* const* d_in, const int* in_sizes, int n_in,
                              void* d_out, int out_size, void* d_ws, size_t ws_size,
                              hipStream_t stream) {
  const float* x  = (const float*)d_in[0];
  const float* Wq = (const float*)d_in[1];
  const float* bq = (const float*)d_in[2];
  const float* Wk = (const float*)d_in[3];
  const float* bk = (const float*)d_in[4];
  const float* Wv = (const float*)d_in[5];
  const float* bv = (const float*)d_in[6];
  float* out = (float*)d_out;

  char* wsb = (char*)d_ws;
  unsigned short* Wt  = (unsigned short*)wsb;                 // 768 KB (tiled W)
  unsigned short* Qg  = (unsigned short*)(wsb + 786432);      // 4 MB
  unsigned short* KVg = (unsigned short*)(wsb + 4980736);     // 8 MB (512 x 16KB tiles)
  unsigned short* Po  = (unsigned short*)(wsb + 13369344);    // 18.9 MB (576 slots, bf16)
  float* Plr = (float*)(wsb + 32243712);                      // 288 KB

  wconv_k<<<dim3(384), dim3(256), 0, stream>>>(Wq, Wk, Wv, Wt);
  proj_k<<<dim3(512), dim3(256), 0, stream>>>(x, bq, bk, bv, Wt, Qg, KVg);
  attn_k<<<dim3(576), dim3(256), 0, stream>>>(Qg, KVg, Po, Plr);
  combine_k<<<dim3(512), dim3(256), 0, stream>>>(Po, Plr, out);
}